// Round 23
// baseline (89.382 us; speedup 1.0000x reference)
//
#include <hip/hip_runtime.h>
#include <math.h>

#define Bv  4
#define Cv  64
#define DCv 32
#define Fv  128
#define Tv  512
#define FT  (Fv * 512)

typedef __attribute__((ext_vector_type(8))) short bf16x8;
typedef __attribute__((ext_vector_type(4))) float f32x4;

__device__ __forceinline__ unsigned f2bf(float x) {          // RNE pack
    unsigned u = __float_as_uint(x);
    return (u + 0x7FFFu + ((u >> 16) & 1u)) >> 16;
}

// ---------------------------------------------------------------------------
// KC1: conv1, 8-row x 4-t register tile (~27 us). [BYTE-IDENTICAL champion]
// ---------------------------------------------------------------------------
__global__ __launch_bounds__(256, 4)
void kc1_conv(const float* __restrict__ inp,
              const float* __restrict__ w1, const float* __restrict__ b1,
              const float* __restrict__ g1, const float* __restrict__ be1,
              const float* __restrict__ m1, const float* __restrict__ v1,
              const float* __restrict__ a1,
              float* __restrict__ Qws)
{
    __shared__ __align__(16) float sW[Cv * DCv];   // 8 KB [k][c]
    __shared__ float sB[DCv];

    const int tid = threadIdx.x;
    const int bid = blockIdx.x;
    const int h   = bid & 1;
    const int bf  = bid >> 1;
    const int b   = bf >> 7;
    const int f   = bf & 127;

    #pragma unroll
    for (int i = 0; i < 8; ++i) {
        const int e = tid * 8 + i;
        const int c = e & 31, k = e >> 5;
        sW[e] = w1[c * Cv + k] * (g1[c] * rsqrtf(v1[c] + 1e-5f));
    }
    if (tid < DCv) {
        const float s = g1[tid] * rsqrtf(v1[tid] + 1e-5f);
        sB[tid] = (b1[tid] - m1[tid]) * s + be1[tid];
    }
    const float alpha1 = a1[0];
    __syncthreads();

    const int w  = tid >> 6, l = tid & 63;
    const int tl = l & 15, cl = l >> 4;
    const int r0 = cl * 8;
    const int t0 = h * 256 + w * 64 + tl * 4;

    const float* px = inp + (size_t)(b * Cv) * FT + f * 512 + t0;

    float acc[32];
    #pragma unroll
    for (int i = 0; i < 32; ++i) acc[i] = 0.f;

    #pragma unroll 8
    for (int k = 0; k < Cv; ++k) {
        const float4 x   = *(const float4*)&px[(size_t)k * FT];
        const float4 a0  = *(const float4*)&sW[k * DCv + r0];
        const float4 a1v = *(const float4*)&sW[k * DCv + r0 + 4];
        acc[0*4+0] = fmaf(a0.x, x.x, acc[0*4+0]); acc[0*4+1] = fmaf(a0.x, x.y, acc[0*4+1]);
        acc[0*4+2] = fmaf(a0.x, x.z, acc[0*4+2]); acc[0*4+3] = fmaf(a0.x, x.w, acc[0*4+3]);
        acc[1*4+0] = fmaf(a0.y, x.x, acc[1*4+0]); acc[1*4+1] = fmaf(a0.y, x.y, acc[1*4+1]);
        acc[1*4+2] = fmaf(a0.y, x.z, acc[1*4+2]); acc[1*4+3] = fmaf(a0.y, x.w, acc[1*4+3]);
        acc[2*4+0] = fmaf(a0.z, x.x, acc[2*4+0]); acc[2*4+1] = fmaf(a0.z, x.y, acc[2*4+1]);
        acc[2*4+2] = fmaf(a0.z, x.z, acc[2*4+2]); acc[2*4+3] = fmaf(a0.z, x.w, acc[2*4+3]);
        acc[3*4+0] = fmaf(a0.w, x.x, acc[3*4+0]); acc[3*4+1] = fmaf(a0.w, x.y, acc[3*4+1]);
        acc[3*4+2] = fmaf(a0.w, x.z, acc[3*4+2]); acc[3*4+3] = fmaf(a0.w, x.w, acc[3*4+3]);
        acc[4*4+0] = fmaf(a1v.x, x.x, acc[4*4+0]); acc[4*4+1] = fmaf(a1v.x, x.y, acc[4*4+1]);
        acc[4*4+2] = fmaf(a1v.x, x.z, acc[4*4+2]); acc[4*4+3] = fmaf(a1v.x, x.w, acc[4*4+3]);
        acc[5*4+0] = fmaf(a1v.y, x.x, acc[5*4+0]); acc[5*4+1] = fmaf(a1v.y, x.y, acc[5*4+1]);
        acc[5*4+2] = fmaf(a1v.y, x.z, acc[5*4+2]); acc[5*4+3] = fmaf(a1v.y, x.w, acc[5*4+3]);
        acc[6*4+0] = fmaf(a1v.z, x.x, acc[6*4+0]); acc[6*4+1] = fmaf(a1v.z, x.y, acc[6*4+1]);
        acc[6*4+2] = fmaf(a1v.z, x.z, acc[6*4+2]); acc[6*4+3] = fmaf(a1v.z, x.w, acc[6*4+3]);
        acc[7*4+0] = fmaf(a1v.w, x.x, acc[7*4+0]); acc[7*4+1] = fmaf(a1v.w, x.y, acc[7*4+1]);
        acc[7*4+2] = fmaf(a1v.w, x.z, acc[7*4+2]); acc[7*4+3] = fmaf(a1v.w, x.w, acc[7*4+3]);
    }

    const float b0 = sB[r0+0], b1_ = sB[r0+1], b2 = sB[r0+2], b3 = sB[r0+3];
    const float b4 = sB[r0+4], b5  = sB[r0+5], b6 = sB[r0+6], b7 = sB[r0+7];
    #pragma unroll
    for (int j = 0; j < 4; ++j) {
        float z0 = acc[0*4+j] + b0, z1 = acc[1*4+j] + b1_;
        float z2 = acc[2*4+j] + b2, z3 = acc[3*4+j] + b3;
        float z4 = acc[4*4+j] + b4, z5 = acc[5*4+j] + b5;
        float z6 = acc[6*4+j] + b6, z7 = acc[7*4+j] + b7;
        z0 = z0 >= 0.f ? z0 : alpha1 * z0;  z1 = z1 >= 0.f ? z1 : alpha1 * z1;
        z2 = z2 >= 0.f ? z2 : alpha1 * z2;  z3 = z3 >= 0.f ? z3 : alpha1 * z3;
        z4 = z4 >= 0.f ? z4 : alpha1 * z4;  z5 = z5 >= 0.f ? z5 : alpha1 * z5;
        z6 = z6 >= 0.f ? z6 : alpha1 * z6;  z7 = z7 >= 0.f ? z7 : alpha1 * z7;
        float4 v0; v0.x = z0; v0.y = z1; v0.z = z2; v0.w = z3;
        float4 v1; v1.x = z4; v1.y = z5; v1.z = z6; v1.w = z7;
        float* qg = Qws + ((size_t)bf * Tv + t0 + j) * DCv + r0;
        *(float4*)&qg[0] = v0;
        *(float4*)&qg[4] = v1;
    }
}

// ---------------------------------------------------------------------------
// KM: M = Q Q^T / sqrt(32). One block per bf (~9 us). [BYTE-IDENTICAL]
// ---------------------------------------------------------------------------
__global__ __launch_bounds__(256)
void km_build(const float* __restrict__ Qws, float* __restrict__ Mfull)
{
    __shared__ __align__(16) float sP[4][1024];  // 16 KB

    const int tid   = threadIdx.x;
    const int bf    = blockIdx.x;
    const int slice = tid >> 6;
    const int l     = tid & 63;
    const int c1b   = l >> 3;
    const int c2b   = l & 7;

    const float* qp = Qws + ((size_t)bf * Tv + slice * 128) * DCv;
    float4 r0 = {0,0,0,0}, r1 = {0,0,0,0}, r2 = {0,0,0,0}, r3 = {0,0,0,0};
    #pragma unroll 4
    for (int i = 0; i < 128; ++i) {
        const float4 qa = *(const float4*)&qp[i * 32 + c1b * 4];
        const float4 qb = *(const float4*)&qp[i * 32 + c2b * 4];
        r0.x = fmaf(qa.x, qb.x, r0.x); r0.y = fmaf(qa.x, qb.y, r0.y);
        r0.z = fmaf(qa.x, qb.z, r0.z); r0.w = fmaf(qa.x, qb.w, r0.w);
        r1.x = fmaf(qa.y, qb.x, r1.x); r1.y = fmaf(qa.y, qb.y, r1.y);
        r1.z = fmaf(qa.y, qb.z, r1.z); r1.w = fmaf(qa.y, qb.w, r1.w);
        r2.x = fmaf(qa.z, qb.x, r2.x); r2.y = fmaf(qa.z, qb.y, r2.y);
        r2.z = fmaf(qa.z, qb.z, r2.z); r2.w = fmaf(qa.z, qb.w, r2.w);
        r3.x = fmaf(qa.w, qb.x, r3.x); r3.y = fmaf(qa.w, qb.y, r3.y);
        r3.z = fmaf(qa.w, qb.z, r3.z); r3.w = fmaf(qa.w, qb.w, r3.w);
    }
    *(float4*)&sP[slice][(c1b * 4 + 0) * DCv + c2b * 4] = r0;
    *(float4*)&sP[slice][(c1b * 4 + 1) * DCv + c2b * 4] = r1;
    *(float4*)&sP[slice][(c1b * 4 + 2) * DCv + c2b * 4] = r2;
    *(float4*)&sP[slice][(c1b * 4 + 3) * DCv + c2b * 4] = r3;
    __syncthreads();

    const float INV = 0.17677669529663687f;  // 1/sqrt(32)
    float4 v0 = *(const float4*)&sP[0][tid * 4];
    float4 v1 = *(const float4*)&sP[1][tid * 4];
    float4 v2 = *(const float4*)&sP[2][tid * 4];
    float4 v3 = *(const float4*)&sP[3][tid * 4];
    float4 o;
    o.x = ((v0.x + v1.x) + (v2.x + v3.x)) * INV;
    o.y = ((v0.y + v1.y) + (v2.y + v3.y)) * INV;
    o.z = ((v0.z + v1.z) + (v2.z + v3.z)) * INV;
    o.w = ((v0.w + v1.w) + (v2.w + v3.w)) * INV;
    *(float4*)&Mfull[(size_t)bf * 1024 + tid * 4] = o;
}

// ---------------------------------------------------------------------------
// KF v5: GEMM1 fp32 (champion path) -> online softmax -> P as bf16 [t][40]
// (aliases dead sX) -> GEMM2 via MFMA 16x16x32 bf16 (K=32 in ONE mfma; 16
// MFMAs + 8 fragment loads/wave replace 192 ds_read_b128 + 1024 FMA/thread).
// W2 (BN-folded) staged bf16 [64][40]. Epilogue per C/D layout (m89):
// col=lane&15, row=(lane>>4)*4+reg.
// ---------------------------------------------------------------------------
#define GEMM_CC(ACC, cc, a)                                       \
    ACC[(cc)*4+0] = fmaf(a.x, x0.x, ACC[(cc)*4+0]);               \
    ACC[(cc)*4+0] = fmaf(a.y, x1.x, ACC[(cc)*4+0]);               \
    ACC[(cc)*4+0] = fmaf(a.z, x2.x, ACC[(cc)*4+0]);               \
    ACC[(cc)*4+0] = fmaf(a.w, x3.x, ACC[(cc)*4+0]);               \
    ACC[(cc)*4+1] = fmaf(a.x, x0.y, ACC[(cc)*4+1]);               \
    ACC[(cc)*4+1] = fmaf(a.y, x1.y, ACC[(cc)*4+1]);               \
    ACC[(cc)*4+1] = fmaf(a.z, x2.y, ACC[(cc)*4+1]);               \
    ACC[(cc)*4+1] = fmaf(a.w, x3.y, ACC[(cc)*4+1]);               \
    ACC[(cc)*4+2] = fmaf(a.x, x0.z, ACC[(cc)*4+2]);               \
    ACC[(cc)*4+2] = fmaf(a.y, x1.z, ACC[(cc)*4+2]);               \
    ACC[(cc)*4+2] = fmaf(a.z, x2.z, ACC[(cc)*4+2]);               \
    ACC[(cc)*4+2] = fmaf(a.w, x3.z, ACC[(cc)*4+2]);               \
    ACC[(cc)*4+3] = fmaf(a.x, x0.w, ACC[(cc)*4+3]);               \
    ACC[(cc)*4+3] = fmaf(a.y, x1.w, ACC[(cc)*4+3]);               \
    ACC[(cc)*4+3] = fmaf(a.z, x2.w, ACC[(cc)*4+3]);               \
    ACC[(cc)*4+3] = fmaf(a.w, x3.w, ACC[(cc)*4+3]);

__global__ __launch_bounds__(512, 2)
void kf_fused(const float* __restrict__ inp,
              const float* __restrict__ Qws, const float* __restrict__ Mfull,
              const float* __restrict__ wp, const float* __restrict__ bp,
              const float* __restrict__ g2, const float* __restrict__ be2,
              const float* __restrict__ m2, const float* __restrict__ v2,
              const float* __restrict__ a2,
              float* __restrict__ out)
{
    __shared__ __align__(16) float sX[DCv * Tv];          // 64 KB: Q fp32 [k][t], later P bf16 [t][40]
    __shared__ __align__(16) float sM[DCv * 36];          // 4.5 KB
    __shared__ __align__(16) unsigned short sWb[Cv * 40]; // 5 KB: W2 bf16 [oc][k] pad40
    __shared__ float sPartM[8][DCv], sPartS[8][DCv];
    __shared__ float sMx[DCv], sRZ[DCv];
    __shared__ float sB2[Cv];

    const int tid = threadIdx.x;
    const int bf  = blockIdx.x;
    const int b   = bf >> 7;
    const int f   = bf & 127;
    const int w   = tid >> 6;
    const int l   = tid & 63;
    const int tl  = l & 15;
    const int cl  = l >> 4;
    const int t0  = w * 64 + tl * 4;          // this lane's 4 t-columns
    const int limit = f + (Tv - Fv + 1);      // valid iff t < limit (385..512)
    const float alpha2 = a2[0];

    // ---- stage: q column, M (fp32), W2 bf16 (BN-folded), B2 ----
    const float* qg = Qws + ((size_t)bf * Tv + tid) * DCv;
    float4 q0 = *(const float4*)&qg[0],  q1 = *(const float4*)&qg[4];
    float4 q2 = *(const float4*)&qg[8],  q3 = *(const float4*)&qg[12];
    float4 q4 = *(const float4*)&qg[16], q5 = *(const float4*)&qg[20];
    float4 q6 = *(const float4*)&qg[24], q7 = *(const float4*)&qg[28];

    if (tid < 256) {
        const int c = tid >> 3, k0 = (tid & 7) << 2;
        float4 v = *(const float4*)&Mfull[(size_t)bf * 1024 + tid * 4];
        *(float4*)&sM[c * 36 + k0] = v;
    }
    {
        const int oc = tid >> 3, k0 = (tid & 7) << 2;
        const float s = g2[oc] * rsqrtf(v2[oc] + 1e-5f);
        float4 v = *(const float4*)&wp[tid * 4];
        unsigned short* d = &sWb[oc * 40 + k0];
        d[0] = (unsigned short)f2bf(v.x * s);
        d[1] = (unsigned short)f2bf(v.y * s);
        d[2] = (unsigned short)f2bf(v.z * s);
        d[3] = (unsigned short)f2bf(v.w * s);
    }
    if (tid < Cv) {
        const float s = g2[tid] * rsqrtf(v2[tid] + 1e-5f);
        sB2[tid] = (bp[tid] - m2[tid]) * s + be2[tid];
    }

    {
        const int t = tid;
        sX[ 0*Tv+t]=q0.x; sX[ 1*Tv+t]=q0.y; sX[ 2*Tv+t]=q0.z; sX[ 3*Tv+t]=q0.w;
        sX[ 4*Tv+t]=q1.x; sX[ 5*Tv+t]=q1.y; sX[ 6*Tv+t]=q1.z; sX[ 7*Tv+t]=q1.w;
        sX[ 8*Tv+t]=q2.x; sX[ 9*Tv+t]=q2.y; sX[10*Tv+t]=q2.z; sX[11*Tv+t]=q2.w;
        sX[12*Tv+t]=q3.x; sX[13*Tv+t]=q3.y; sX[14*Tv+t]=q3.z; sX[15*Tv+t]=q3.w;
        sX[16*Tv+t]=q4.x; sX[17*Tv+t]=q4.y; sX[18*Tv+t]=q4.z; sX[19*Tv+t]=q4.w;
        sX[20*Tv+t]=q5.x; sX[21*Tv+t]=q5.y; sX[22*Tv+t]=q5.z; sX[23*Tv+t]=q5.w;
        sX[24*Tv+t]=q6.x; sX[25*Tv+t]=q6.y; sX[26*Tv+t]=q6.z; sX[27*Tv+t]=q6.w;
        sX[28*Tv+t]=q7.x; sX[29*Tv+t]=q7.y; sX[30*Tv+t]=q7.z; sX[31*Tv+t]=q7.w;
    }
    __syncthreads();

    // ---- GEMM1 (fp32): O[32c][t], two 4-row tiles sharing x-reads ----
    float oA[16], oB[16];
    #pragma unroll
    for (int i = 0; i < 16; ++i) { oA[i] = 0.f; oB[i] = 0.f; }
    const int cA = cl * 4;
    const int cB = 16 + cl * 4;
    #pragma unroll
    for (int k0 = 0; k0 < 32; k0 += 4) {
        const float4 x0 = *(const float4*)&sX[(k0+0)*Tv + t0];
        const float4 x1 = *(const float4*)&sX[(k0+1)*Tv + t0];
        const float4 x2 = *(const float4*)&sX[(k0+2)*Tv + t0];
        const float4 x3 = *(const float4*)&sX[(k0+3)*Tv + t0];
        { const float4 a = *(const float4*)&sM[(cA+0)*36 + k0]; GEMM_CC(oA,0,a) }
        { const float4 a = *(const float4*)&sM[(cA+1)*36 + k0]; GEMM_CC(oA,1,a) }
        { const float4 a = *(const float4*)&sM[(cA+2)*36 + k0]; GEMM_CC(oA,2,a) }
        { const float4 a = *(const float4*)&sM[(cA+3)*36 + k0]; GEMM_CC(oA,3,a) }
        { const float4 a = *(const float4*)&sM[(cB+0)*36 + k0]; GEMM_CC(oB,0,a) }
        { const float4 a = *(const float4*)&sM[(cB+1)*36 + k0]; GEMM_CC(oB,1,a) }
        { const float4 a = *(const float4*)&sM[(cB+2)*36 + k0]; GEMM_CC(oB,2,a) }
        { const float4 a = *(const float4*)&sM[(cB+3)*36 + k0]; GEMM_CC(oB,3,a) }
    }

    // ---- mask ----
    #pragma unroll
    for (int jt = 0; jt < 4; ++jt) {
        if (t0 + jt >= limit) {
            #pragma unroll
            for (int cc = 0; cc < 4; ++cc) { oA[cc*4+jt] = -INFINITY; oB[cc*4+jt] = -INFINITY; }
        }
    }

    // ---- ONLINE wave stats (one pass): m_w, s_w ----
    float mwA[4], mwB[4];
    #pragma unroll
    for (int cc = 0; cc < 4; ++cc) {
        float mA = fmaxf(fmaxf(oA[cc*4+0], oA[cc*4+1]), fmaxf(oA[cc*4+2], oA[cc*4+3]));
        float mB = fmaxf(fmaxf(oB[cc*4+0], oB[cc*4+1]), fmaxf(oB[cc*4+2], oB[cc*4+3]));
        #pragma unroll
        for (int s = 1; s < 16; s <<= 1) {
            mA = fmaxf(mA, __shfl_xor(mA, s));
            mB = fmaxf(mB, __shfl_xor(mB, s));
        }
        mA = fmaxf(mA, -1e30f);
        mB = fmaxf(mB, -1e30f);
        float sA = 0.f, sB = 0.f;
        #pragma unroll
        for (int jt = 0; jt < 4; ++jt) {
            oA[cc*4+jt] = __expf(oA[cc*4+jt] - mA); sA += oA[cc*4+jt];
            oB[cc*4+jt] = __expf(oB[cc*4+jt] - mB); sB += oB[cc*4+jt];
        }
        #pragma unroll
        for (int s = 1; s < 16; s <<= 1) {
            sA += __shfl_xor(sA, s);
            sB += __shfl_xor(sB, s);
        }
        mwA[cc] = mA; mwB[cc] = mB;
        if (tl == 0) {
            sPartM[w][cA + cc] = mA; sPartS[w][cA + cc] = sA;
            sPartM[w][cB + cc] = mB; sPartS[w][cB + cc] = sB;
        }
    }
    __syncthreads();
    if (tid < DCv) {
        float m = sPartM[0][tid];
        #pragma unroll
        for (int ww = 1; ww < 8; ++ww) m = fmaxf(m, sPartM[ww][tid]);
        float Z = 0.f;
        #pragma unroll
        for (int ww = 0; ww < 8; ++ww) Z += sPartS[ww][tid] * __expf(sPartM[ww][tid] - m);
        sMx[tid] = m;
        sRZ[tid] = 1.f / Z;
    }
    __syncthreads();   // also: all GEMM1 reads of sX complete -> safe to alias

    // ---- P (bf16) -> sPb[t][40] aliasing sX ----
    unsigned short* sPb = (unsigned short*)sX;
    {
        float scAv[4], scBv[4];
        #pragma unroll
        for (int cc = 0; cc < 4; ++cc) {
            scAv[cc] = __expf(mwA[cc] - sMx[cA + cc]) * sRZ[cA + cc];
            scBv[cc] = __expf(mwB[cc] - sMx[cB + cc]) * sRZ[cB + cc];
        }
        #pragma unroll
        for (int jt = 0; jt < 4; ++jt) {
            const int t = t0 + jt;
            uint2 va, vb;
            va.x = f2bf(oA[0*4+jt]*scAv[0]) | (f2bf(oA[1*4+jt]*scAv[1]) << 16);
            va.y = f2bf(oA[2*4+jt]*scAv[2]) | (f2bf(oA[3*4+jt]*scAv[3]) << 16);
            vb.x = f2bf(oB[0*4+jt]*scBv[0]) | (f2bf(oB[1*4+jt]*scBv[1]) << 16);
            vb.y = f2bf(oB[2*4+jt]*scBv[2]) | (f2bf(oB[3*4+jt]*scBv[3]) << 16);
            *(uint2*)&sPb[t * 40 + cA] = va;
            *(uint2*)&sPb[t * 40 + cB] = vb;
        }
    }
    __syncthreads();

    // ---- GEMM2 via MFMA: wave w owns t-tiles w*4..w*4+3, all 4 oc-tiles ----
    {
        const int lr = l & 15, lk = l >> 4;      // fragment row/col, k-group
        bf16x8 afr[4];
        #pragma unroll
        for (int o = 0; o < 4; ++o)
            afr[o] = *(bf16x8*)&sWb[(o * 16 + lr) * 40 + lk * 8];
        const int rhi = lk * 4;

        #pragma unroll
        for (int tt = 0; tt < 4; ++tt) {
            const int tbase = (w * 4 + tt) * 16;
            const bf16x8 bfr = *(bf16x8*)&sPb[(tbase + lr) * 40 + lk * 8];
            const int colg = tbase + lr;
            #pragma unroll
            for (int o = 0; o < 4; ++o) {
                f32x4 d = {0.f, 0.f, 0.f, 0.f};
                d = __builtin_amdgcn_mfma_f32_16x16x32_bf16(afr[o], bfr, d, 0, 0, 0);
                const int ocr = o * 16 + rhi;
                const float* rp = inp + ((size_t)(b * Cv + ocr) * Fv + f) * Tv + colg;
                float*       po = out + ((size_t)(b * Cv + ocr) * Fv + f) * Tv + colg;
                #pragma unroll
                for (int r = 0; r < 4; ++r) {
                    float z = d[r] + sB2[ocr + r];
                    z = z >= 0.f ? z : alpha2 * z;
                    po[(size_t)r * FT] = z + rp[(size_t)r * FT];
                }
            }
        }
    }
}

extern "C" void kernel_launch(void* const* d_in, const int* in_sizes, int n_in,
                              void* d_out, int out_size, void* d_ws, size_t ws_size,
                              hipStream_t stream) {
    const float* inp = (const float*)d_in[0];
    const float* w1  = (const float*)d_in[1];
    const float* b1  = (const float*)d_in[2];
    const float* g1  = (const float*)d_in[3];
    const float* be1 = (const float*)d_in[4];
    const float* m1  = (const float*)d_in[5];
    const float* v1  = (const float*)d_in[6];
    const float* a1  = (const float*)d_in[7];
    const float* wp  = (const float*)d_in[8];
    const float* bp  = (const float*)d_in[9];
    const float* g2  = (const float*)d_in[10];
    const float* be2 = (const float*)d_in[11];
    const float* m2  = (const float*)d_in[12];
    const float* v2  = (const float*)d_in[13];
    const float* a2  = (const float*)d_in[14];

    float* Qws   = (float*)d_ws;                            // 8,388,608 f = 33.6 MB
    float* Mfull = Qws + (size_t)Bv * Fv * Tv * DCv;        //   524,288 f =  2.1 MB

    kc1_conv<<<dim3(Bv * Fv * 2), dim3(256), 0, stream>>>(
        inp, w1, b1, g1, be1, m1, v1, a1, Qws);
    km_build<<<dim3(Bv * Fv), dim3(256), 0, stream>>>(Qws, Mfull);
    kf_fused<<<dim3(Bv * Fv), dim3(512), 0, stream>>>(
        inp, Qws, Mfull, wp, bp, g2, be2, m2, v2, a2, (float*)d_out);
}

// Round 24
// 82.188 us; speedup vs baseline: 1.0875x; 1.0875x over previous
//
#include <hip/hip_runtime.h>
#include <math.h>

#define Bv  4
#define Cv  64
#define DCv 32
#define Fv  128
#define Tv  512
#define FT  (Fv * 512)

typedef __attribute__((ext_vector_type(8))) short bf16x8;
typedef __attribute__((ext_vector_type(4))) float f32x4;

__device__ __forceinline__ unsigned f2bf(float x) {          // RNE pack
    unsigned u = __float_as_uint(x);
    return (u + 0x7FFFu + ((u >> 16) & 1u)) >> 16;
}

// ---------------------------------------------------------------------------
// KC1: conv1, 8-row x 4-t register tile (~27 us). [BYTE-IDENTICAL champion]
// ---------------------------------------------------------------------------
__global__ __launch_bounds__(256, 4)
void kc1_conv(const float* __restrict__ inp,
              const float* __restrict__ w1, const float* __restrict__ b1,
              const float* __restrict__ g1, const float* __restrict__ be1,
              const float* __restrict__ m1, const float* __restrict__ v1,
              const float* __restrict__ a1,
              float* __restrict__ Qws)
{
    __shared__ __align__(16) float sW[Cv * DCv];   // 8 KB [k][c]
    __shared__ float sB[DCv];

    const int tid = threadIdx.x;
    const int bid = blockIdx.x;
    const int h   = bid & 1;
    const int bf  = bid >> 1;
    const int b   = bf >> 7;
    const int f   = bf & 127;

    #pragma unroll
    for (int i = 0; i < 8; ++i) {
        const int e = tid * 8 + i;
        const int c = e & 31, k = e >> 5;
        sW[e] = w1[c * Cv + k] * (g1[c] * rsqrtf(v1[c] + 1e-5f));
    }
    if (tid < DCv) {
        const float s = g1[tid] * rsqrtf(v1[tid] + 1e-5f);
        sB[tid] = (b1[tid] - m1[tid]) * s + be1[tid];
    }
    const float alpha1 = a1[0];
    __syncthreads();

    const int w  = tid >> 6, l = tid & 63;
    const int tl = l & 15, cl = l >> 4;
    const int r0 = cl * 8;
    const int t0 = h * 256 + w * 64 + tl * 4;

    const float* px = inp + (size_t)(b * Cv) * FT + f * 512 + t0;

    float acc[32];
    #pragma unroll
    for (int i = 0; i < 32; ++i) acc[i] = 0.f;

    #pragma unroll 8
    for (int k = 0; k < Cv; ++k) {
        const float4 x   = *(const float4*)&px[(size_t)k * FT];
        const float4 a0  = *(const float4*)&sW[k * DCv + r0];
        const float4 a1v = *(const float4*)&sW[k * DCv + r0 + 4];
        acc[0*4+0] = fmaf(a0.x, x.x, acc[0*4+0]); acc[0*4+1] = fmaf(a0.x, x.y, acc[0*4+1]);
        acc[0*4+2] = fmaf(a0.x, x.z, acc[0*4+2]); acc[0*4+3] = fmaf(a0.x, x.w, acc[0*4+3]);
        acc[1*4+0] = fmaf(a0.y, x.x, acc[1*4+0]); acc[1*4+1] = fmaf(a0.y, x.y, acc[1*4+1]);
        acc[1*4+2] = fmaf(a0.y, x.z, acc[1*4+2]); acc[1*4+3] = fmaf(a0.y, x.w, acc[1*4+3]);
        acc[2*4+0] = fmaf(a0.z, x.x, acc[2*4+0]); acc[2*4+1] = fmaf(a0.z, x.y, acc[2*4+1]);
        acc[2*4+2] = fmaf(a0.z, x.z, acc[2*4+2]); acc[2*4+3] = fmaf(a0.z, x.w, acc[2*4+3]);
        acc[3*4+0] = fmaf(a0.w, x.x, acc[3*4+0]); acc[3*4+1] = fmaf(a0.w, x.y, acc[3*4+1]);
        acc[3*4+2] = fmaf(a0.w, x.z, acc[3*4+2]); acc[3*4+3] = fmaf(a0.w, x.w, acc[3*4+3]);
        acc[4*4+0] = fmaf(a1v.x, x.x, acc[4*4+0]); acc[4*4+1] = fmaf(a1v.x, x.y, acc[4*4+1]);
        acc[4*4+2] = fmaf(a1v.x, x.z, acc[4*4+2]); acc[4*4+3] = fmaf(a1v.x, x.w, acc[4*4+3]);
        acc[5*4+0] = fmaf(a1v.y, x.x, acc[5*4+0]); acc[5*4+1] = fmaf(a1v.y, x.y, acc[5*4+1]);
        acc[5*4+2] = fmaf(a1v.y, x.z, acc[5*4+2]); acc[5*4+3] = fmaf(a1v.y, x.w, acc[5*4+3]);
        acc[6*4+0] = fmaf(a1v.z, x.x, acc[6*4+0]); acc[6*4+1] = fmaf(a1v.z, x.y, acc[6*4+1]);
        acc[6*4+2] = fmaf(a1v.z, x.z, acc[6*4+2]); acc[6*4+3] = fmaf(a1v.z, x.w, acc[6*4+3]);
        acc[7*4+0] = fmaf(a1v.w, x.x, acc[7*4+0]); acc[7*4+1] = fmaf(a1v.w, x.y, acc[7*4+1]);
        acc[7*4+2] = fmaf(a1v.w, x.z, acc[7*4+2]); acc[7*4+3] = fmaf(a1v.w, x.w, acc[7*4+3]);
    }

    const float b0 = sB[r0+0], b1_ = sB[r0+1], b2 = sB[r0+2], b3 = sB[r0+3];
    const float b4 = sB[r0+4], b5  = sB[r0+5], b6 = sB[r0+6], b7 = sB[r0+7];
    #pragma unroll
    for (int j = 0; j < 4; ++j) {
        float z0 = acc[0*4+j] + b0, z1 = acc[1*4+j] + b1_;
        float z2 = acc[2*4+j] + b2, z3 = acc[3*4+j] + b3;
        float z4 = acc[4*4+j] + b4, z5 = acc[5*4+j] + b5;
        float z6 = acc[6*4+j] + b6, z7 = acc[7*4+j] + b7;
        z0 = z0 >= 0.f ? z0 : alpha1 * z0;  z1 = z1 >= 0.f ? z1 : alpha1 * z1;
        z2 = z2 >= 0.f ? z2 : alpha1 * z2;  z3 = z3 >= 0.f ? z3 : alpha1 * z3;
        z4 = z4 >= 0.f ? z4 : alpha1 * z4;  z5 = z5 >= 0.f ? z5 : alpha1 * z5;
        z6 = z6 >= 0.f ? z6 : alpha1 * z6;  z7 = z7 >= 0.f ? z7 : alpha1 * z7;
        float4 v0; v0.x = z0; v0.y = z1; v0.z = z2; v0.w = z3;
        float4 v1; v1.x = z4; v1.y = z5; v1.z = z6; v1.w = z7;
        float* qg = Qws + ((size_t)bf * Tv + t0 + j) * DCv + r0;
        *(float4*)&qg[0] = v0;
        *(float4*)&qg[4] = v1;
    }
}

// ---------------------------------------------------------------------------
// KM: M = Q Q^T / sqrt(32). One block per bf (~9 us). [BYTE-IDENTICAL]
// ---------------------------------------------------------------------------
__global__ __launch_bounds__(256)
void km_build(const float* __restrict__ Qws, float* __restrict__ Mfull)
{
    __shared__ __align__(16) float sP[4][1024];  // 16 KB

    const int tid   = threadIdx.x;
    const int bf    = blockIdx.x;
    const int slice = tid >> 6;
    const int l     = tid & 63;
    const int c1b   = l >> 3;
    const int c2b   = l & 7;

    const float* qp = Qws + ((size_t)bf * Tv + slice * 128) * DCv;
    float4 r0 = {0,0,0,0}, r1 = {0,0,0,0}, r2 = {0,0,0,0}, r3 = {0,0,0,0};
    #pragma unroll 4
    for (int i = 0; i < 128; ++i) {
        const float4 qa = *(const float4*)&qp[i * 32 + c1b * 4];
        const float4 qb = *(const float4*)&qp[i * 32 + c2b * 4];
        r0.x = fmaf(qa.x, qb.x, r0.x); r0.y = fmaf(qa.x, qb.y, r0.y);
        r0.z = fmaf(qa.x, qb.z, r0.z); r0.w = fmaf(qa.x, qb.w, r0.w);
        r1.x = fmaf(qa.y, qb.x, r1.x); r1.y = fmaf(qa.y, qb.y, r1.y);
        r1.z = fmaf(qa.y, qb.z, r1.z); r1.w = fmaf(qa.y, qb.w, r1.w);
        r2.x = fmaf(qa.z, qb.x, r2.x); r2.y = fmaf(qa.z, qb.y, r2.y);
        r2.z = fmaf(qa.z, qb.z, r2.z); r2.w = fmaf(qa.z, qb.w, r2.w);
        r3.x = fmaf(qa.w, qb.x, r3.x); r3.y = fmaf(qa.w, qb.y, r3.y);
        r3.z = fmaf(qa.w, qb.z, r3.z); r3.w = fmaf(qa.w, qb.w, r3.w);
    }
    *(float4*)&sP[slice][(c1b * 4 + 0) * DCv + c2b * 4] = r0;
    *(float4*)&sP[slice][(c1b * 4 + 1) * DCv + c2b * 4] = r1;
    *(float4*)&sP[slice][(c1b * 4 + 2) * DCv + c2b * 4] = r2;
    *(float4*)&sP[slice][(c1b * 4 + 3) * DCv + c2b * 4] = r3;
    __syncthreads();

    const float INV = 0.17677669529663687f;  // 1/sqrt(32)
    float4 v0 = *(const float4*)&sP[0][tid * 4];
    float4 v1 = *(const float4*)&sP[1][tid * 4];
    float4 v2 = *(const float4*)&sP[2][tid * 4];
    float4 v3 = *(const float4*)&sP[3][tid * 4];
    float4 o;
    o.x = ((v0.x + v1.x) + (v2.x + v3.x)) * INV;
    o.y = ((v0.y + v1.y) + (v2.y + v3.y)) * INV;
    o.z = ((v0.z + v1.z) + (v2.z + v3.z)) * INV;
    o.w = ((v0.w + v1.w) + (v2.w + v3.w)) * INV;
    *(float4*)&Mfull[(size_t)bf * 1024 + tid * 4] = o;
}

// ---------------------------------------------------------------------------
// KF v6: GEMM1 fp32 -> online softmax -> P bf16 [t][40] (aliases sX) ->
// GEMM2 via MFMA with SWAPPED operands: D = P * W2^T -> D[t][oc], lane's 4
// regs = 4 consecutive t at fixed oc -> float4 residual loads + float4
// stores (r23's scalar-scatter epilogue was the regression source).
// ---------------------------------------------------------------------------
#define GEMM_CC(ACC, cc, a)                                       \
    ACC[(cc)*4+0] = fmaf(a.x, x0.x, ACC[(cc)*4+0]);               \
    ACC[(cc)*4+0] = fmaf(a.y, x1.x, ACC[(cc)*4+0]);               \
    ACC[(cc)*4+0] = fmaf(a.z, x2.x, ACC[(cc)*4+0]);               \
    ACC[(cc)*4+0] = fmaf(a.w, x3.x, ACC[(cc)*4+0]);               \
    ACC[(cc)*4+1] = fmaf(a.x, x0.y, ACC[(cc)*4+1]);               \
    ACC[(cc)*4+1] = fmaf(a.y, x1.y, ACC[(cc)*4+1]);               \
    ACC[(cc)*4+1] = fmaf(a.z, x2.y, ACC[(cc)*4+1]);               \
    ACC[(cc)*4+1] = fmaf(a.w, x3.y, ACC[(cc)*4+1]);               \
    ACC[(cc)*4+2] = fmaf(a.x, x0.z, ACC[(cc)*4+2]);               \
    ACC[(cc)*4+2] = fmaf(a.y, x1.z, ACC[(cc)*4+2]);               \
    ACC[(cc)*4+2] = fmaf(a.z, x2.z, ACC[(cc)*4+2]);               \
    ACC[(cc)*4+2] = fmaf(a.w, x3.z, ACC[(cc)*4+2]);               \
    ACC[(cc)*4+3] = fmaf(a.x, x0.w, ACC[(cc)*4+3]);               \
    ACC[(cc)*4+3] = fmaf(a.y, x1.w, ACC[(cc)*4+3]);               \
    ACC[(cc)*4+3] = fmaf(a.z, x2.w, ACC[(cc)*4+3]);               \
    ACC[(cc)*4+3] = fmaf(a.w, x3.w, ACC[(cc)*4+3]);

__global__ __launch_bounds__(512, 2)
void kf_fused(const float* __restrict__ inp,
              const float* __restrict__ Qws, const float* __restrict__ Mfull,
              const float* __restrict__ wp, const float* __restrict__ bp,
              const float* __restrict__ g2, const float* __restrict__ be2,
              const float* __restrict__ m2, const float* __restrict__ v2,
              const float* __restrict__ a2,
              float* __restrict__ out)
{
    __shared__ __align__(16) float sX[DCv * Tv];          // 64 KB: Q fp32 [k][t], later P bf16 [t][40]
    __shared__ __align__(16) float sM[DCv * 36];          // 4.5 KB
    __shared__ __align__(16) unsigned short sWb[Cv * 40]; // 5 KB: W2 bf16 [oc][k] pad40
    __shared__ float sPartM[8][DCv], sPartS[8][DCv];
    __shared__ float sMx[DCv], sRZ[DCv];
    __shared__ float sB2[Cv];

    const int tid = threadIdx.x;
    const int bf  = blockIdx.x;
    const int b   = bf >> 7;
    const int f   = bf & 127;
    const int w   = tid >> 6;
    const int l   = tid & 63;
    const int tl  = l & 15;
    const int cl  = l >> 4;
    const int t0  = w * 64 + tl * 4;          // this lane's 4 t-columns
    const int limit = f + (Tv - Fv + 1);      // valid iff t < limit (385..512)
    const float alpha2 = a2[0];

    // ---- stage: q column, M (fp32), W2 bf16 (BN-folded), B2 ----
    const float* qg = Qws + ((size_t)bf * Tv + tid) * DCv;
    float4 q0 = *(const float4*)&qg[0],  q1 = *(const float4*)&qg[4];
    float4 q2 = *(const float4*)&qg[8],  q3 = *(const float4*)&qg[12];
    float4 q4 = *(const float4*)&qg[16], q5 = *(const float4*)&qg[20];
    float4 q6 = *(const float4*)&qg[24], q7 = *(const float4*)&qg[28];

    if (tid < 256) {
        const int c = tid >> 3, k0 = (tid & 7) << 2;
        float4 v = *(const float4*)&Mfull[(size_t)bf * 1024 + tid * 4];
        *(float4*)&sM[c * 36 + k0] = v;
    }
    {
        const int oc = tid >> 3, k0 = (tid & 7) << 2;
        const float s = g2[oc] * rsqrtf(v2[oc] + 1e-5f);
        float4 v = *(const float4*)&wp[tid * 4];
        unsigned short* d = &sWb[oc * 40 + k0];
        d[0] = (unsigned short)f2bf(v.x * s);
        d[1] = (unsigned short)f2bf(v.y * s);
        d[2] = (unsigned short)f2bf(v.z * s);
        d[3] = (unsigned short)f2bf(v.w * s);
    }
    if (tid < Cv) {
        const float s = g2[tid] * rsqrtf(v2[tid] + 1e-5f);
        sB2[tid] = (bp[tid] - m2[tid]) * s + be2[tid];
    }

    {
        const int t = tid;
        sX[ 0*Tv+t]=q0.x; sX[ 1*Tv+t]=q0.y; sX[ 2*Tv+t]=q0.z; sX[ 3*Tv+t]=q0.w;
        sX[ 4*Tv+t]=q1.x; sX[ 5*Tv+t]=q1.y; sX[ 6*Tv+t]=q1.z; sX[ 7*Tv+t]=q1.w;
        sX[ 8*Tv+t]=q2.x; sX[ 9*Tv+t]=q2.y; sX[10*Tv+t]=q2.z; sX[11*Tv+t]=q2.w;
        sX[12*Tv+t]=q3.x; sX[13*Tv+t]=q3.y; sX[14*Tv+t]=q3.z; sX[15*Tv+t]=q3.w;
        sX[16*Tv+t]=q4.x; sX[17*Tv+t]=q4.y; sX[18*Tv+t]=q4.z; sX[19*Tv+t]=q4.w;
        sX[20*Tv+t]=q5.x; sX[21*Tv+t]=q5.y; sX[22*Tv+t]=q5.z; sX[23*Tv+t]=q5.w;
        sX[24*Tv+t]=q6.x; sX[25*Tv+t]=q6.y; sX[26*Tv+t]=q6.z; sX[27*Tv+t]=q6.w;
        sX[28*Tv+t]=q7.x; sX[29*Tv+t]=q7.y; sX[30*Tv+t]=q7.z; sX[31*Tv+t]=q7.w;
    }
    __syncthreads();

    // ---- GEMM1 (fp32): O[32c][t], two 4-row tiles sharing x-reads ----
    float oA[16], oB[16];
    #pragma unroll
    for (int i = 0; i < 16; ++i) { oA[i] = 0.f; oB[i] = 0.f; }
    const int cA = cl * 4;
    const int cB = 16 + cl * 4;
    #pragma unroll
    for (int k0 = 0; k0 < 32; k0 += 4) {
        const float4 x0 = *(const float4*)&sX[(k0+0)*Tv + t0];
        const float4 x1 = *(const float4*)&sX[(k0+1)*Tv + t0];
        const float4 x2 = *(const float4*)&sX[(k0+2)*Tv + t0];
        const float4 x3 = *(const float4*)&sX[(k0+3)*Tv + t0];
        { const float4 a = *(const float4*)&sM[(cA+0)*36 + k0]; GEMM_CC(oA,0,a) }
        { const float4 a = *(const float4*)&sM[(cA+1)*36 + k0]; GEMM_CC(oA,1,a) }
        { const float4 a = *(const float4*)&sM[(cA+2)*36 + k0]; GEMM_CC(oA,2,a) }
        { const float4 a = *(const float4*)&sM[(cA+3)*36 + k0]; GEMM_CC(oA,3,a) }
        { const float4 a = *(const float4*)&sM[(cB+0)*36 + k0]; GEMM_CC(oB,0,a) }
        { const float4 a = *(const float4*)&sM[(cB+1)*36 + k0]; GEMM_CC(oB,1,a) }
        { const float4 a = *(const float4*)&sM[(cB+2)*36 + k0]; GEMM_CC(oB,2,a) }
        { const float4 a = *(const float4*)&sM[(cB+3)*36 + k0]; GEMM_CC(oB,3,a) }
    }

    // ---- mask ----
    #pragma unroll
    for (int jt = 0; jt < 4; ++jt) {
        if (t0 + jt >= limit) {
            #pragma unroll
            for (int cc = 0; cc < 4; ++cc) { oA[cc*4+jt] = -INFINITY; oB[cc*4+jt] = -INFINITY; }
        }
    }

    // ---- ONLINE wave stats (one pass): m_w, s_w ----
    float mwA[4], mwB[4];
    #pragma unroll
    for (int cc = 0; cc < 4; ++cc) {
        float mA = fmaxf(fmaxf(oA[cc*4+0], oA[cc*4+1]), fmaxf(oA[cc*4+2], oA[cc*4+3]));
        float mB = fmaxf(fmaxf(oB[cc*4+0], oB[cc*4+1]), fmaxf(oB[cc*4+2], oB[cc*4+3]));
        #pragma unroll
        for (int s = 1; s < 16; s <<= 1) {
            mA = fmaxf(mA, __shfl_xor(mA, s));
            mB = fmaxf(mB, __shfl_xor(mB, s));
        }
        mA = fmaxf(mA, -1e30f);
        mB = fmaxf(mB, -1e30f);
        float sA = 0.f, sB = 0.f;
        #pragma unroll
        for (int jt = 0; jt < 4; ++jt) {
            oA[cc*4+jt] = __expf(oA[cc*4+jt] - mA); sA += oA[cc*4+jt];
            oB[cc*4+jt] = __expf(oB[cc*4+jt] - mB); sB += oB[cc*4+jt];
        }
        #pragma unroll
        for (int s = 1; s < 16; s <<= 1) {
            sA += __shfl_xor(sA, s);
            sB += __shfl_xor(sB, s);
        }
        mwA[cc] = mA; mwB[cc] = mB;
        if (tl == 0) {
            sPartM[w][cA + cc] = mA; sPartS[w][cA + cc] = sA;
            sPartM[w][cB + cc] = mB; sPartS[w][cB + cc] = sB;
        }
    }
    __syncthreads();
    if (tid < DCv) {
        float m = sPartM[0][tid];
        #pragma unroll
        for (int ww = 1; ww < 8; ++ww) m = fmaxf(m, sPartM[ww][tid]);
        float Z = 0.f;
        #pragma unroll
        for (int ww = 0; ww < 8; ++ww) Z += sPartS[ww][tid] * __expf(sPartM[ww][tid] - m);
        sMx[tid] = m;
        sRZ[tid] = 1.f / Z;
    }
    __syncthreads();   // also: all GEMM1 reads of sX complete -> safe to alias

    // ---- P (bf16) -> sPb[t][40] aliasing sX ----
    unsigned short* sPb = (unsigned short*)sX;
    {
        float scAv[4], scBv[4];
        #pragma unroll
        for (int cc = 0; cc < 4; ++cc) {
            scAv[cc] = __expf(mwA[cc] - sMx[cA + cc]) * sRZ[cA + cc];
            scBv[cc] = __expf(mwB[cc] - sMx[cB + cc]) * sRZ[cB + cc];
        }
        #pragma unroll
        for (int jt = 0; jt < 4; ++jt) {
            const int t = t0 + jt;
            uint2 va, vb;
            va.x = f2bf(oA[0*4+jt]*scAv[0]) | (f2bf(oA[1*4+jt]*scAv[1]) << 16);
            va.y = f2bf(oA[2*4+jt]*scAv[2]) | (f2bf(oA[3*4+jt]*scAv[3]) << 16);
            vb.x = f2bf(oB[0*4+jt]*scBv[0]) | (f2bf(oB[1*4+jt]*scBv[1]) << 16);
            vb.y = f2bf(oB[2*4+jt]*scBv[2]) | (f2bf(oB[3*4+jt]*scBv[3]) << 16);
            *(uint2*)&sPb[t * 40 + cA] = va;
            *(uint2*)&sPb[t * 40 + cB] = vb;
        }
    }
    __syncthreads();

    // ---- GEMM2 via MFMA (SWAPPED): D = P * W2^T -> D[t][oc] ----
    // A (m=t): bfr from sPb row t=tbase+lr; B (n=oc): afr from sWb row oc.
    // C/D: col = oc = lane&15, row = t = (lane>>4)*4 + r -> float4-over-t epilogue.
    {
        const int lr = l & 15, lk = l >> 4;
        bf16x8 afr[4];
        #pragma unroll
        for (int o = 0; o < 4; ++o)
            afr[o] = *(bf16x8*)&sWb[(o * 16 + lr) * 40 + lk * 8];

        #pragma unroll
        for (int tt = 0; tt < 4; ++tt) {
            const int tbase = (w * 4 + tt) * 16;
            const bf16x8 bfr = *(bf16x8*)&sPb[(tbase + lr) * 40 + lk * 8];
            const int trow = tbase + lk * 4;        // this lane's 4 consecutive t
            #pragma unroll
            for (int o = 0; o < 4; ++o) {
                f32x4 d = {0.f, 0.f, 0.f, 0.f};
                d = __builtin_amdgcn_mfma_f32_16x16x32_bf16(bfr, afr[o], d, 0, 0, 0);
                const int oc = o * 16 + lr;
                const float* rp = inp + ((size_t)(b * Cv + oc) * Fv + f) * Tv + trow;
                float*       po = out + ((size_t)(b * Cv + oc) * Fv + f) * Tv + trow;
                const float4 rv = *(const float4*)rp;
                const float bb = sB2[oc];
                float z0 = d[0] + bb, z1 = d[1] + bb, z2 = d[2] + bb, z3 = d[3] + bb;
                z0 = z0 >= 0.f ? z0 : alpha2 * z0;
                z1 = z1 >= 0.f ? z1 : alpha2 * z1;
                z2 = z2 >= 0.f ? z2 : alpha2 * z2;
                z3 = z3 >= 0.f ? z3 : alpha2 * z3;
                float4 o4; o4.x = z0 + rv.x; o4.y = z1 + rv.y;
                o4.z = z2 + rv.z; o4.w = z3 + rv.w;
                *(float4*)po = o4;
            }
        }
    }
}

extern "C" void kernel_launch(void* const* d_in, const int* in_sizes, int n_in,
                              void* d_out, int out_size, void* d_ws, size_t ws_size,
                              hipStream_t stream) {
    const float* inp = (const float*)d_in[0];
    const float* w1  = (const float*)d_in[1];
    const float* b1  = (const float*)d_in[2];
    const float* g1  = (const float*)d_in[3];
    const float* be1 = (const float*)d_in[4];
    const float* m1  = (const float*)d_in[5];
    const float* v1  = (const float*)d_in[6];
    const float* a1  = (const float*)d_in[7];
    const float* wp  = (const float*)d_in[8];
    const float* bp  = (const float*)d_in[9];
    const float* g2  = (const float*)d_in[10];
    const float* be2 = (const float*)d_in[11];
    const float* m2  = (const float*)d_in[12];
    const float* v2  = (const float*)d_in[13];
    const float* a2  = (const float*)d_in[14];

    float* Qws   = (float*)d_ws;                            // 8,388,608 f = 33.6 MB
    float* Mfull = Qws + (size_t)Bv * Fv * Tv * DCv;        //   524,288 f =  2.1 MB

    kc1_conv<<<dim3(Bv * Fv * 2), dim3(256), 0, stream>>>(
        inp, w1, b1, g1, be1, m1, v1, a1, Qws);
    km_build<<<dim3(Bv * Fv), dim3(256), 0, stream>>>(Qws, Mfull);
    kf_fused<<<dim3(Bv * Fv), dim3(512), 0, stream>>>(
        inp, Qws, Mfull, wp, bp, g2, be2, m2, v2, a2, (float*)d_out);
}

// Round 26
// 81.852 us; speedup vs baseline: 1.0920x; 1.0041x over previous
//
#include <hip/hip_runtime.h>
#include <math.h>

#define Bv  4
#define Cv  64
#define DCv 32
#define Fv  128
#define Tv  512
#define FT  (Fv * 512)

typedef __attribute__((ext_vector_type(8))) short bf16x8;
typedef __attribute__((ext_vector_type(4))) float f32x4;

__device__ __forceinline__ unsigned f2bf(float x) {          // RNE pack
    unsigned u = __float_as_uint(x);
    return (u + 0x7FFFu + ((u >> 16) & 1u)) >> 16;
}

// ---------------------------------------------------------------------------
// KC1: conv1, 8-row x 4-t register tile (~27 us). [r24 champion, fp32 Q]
// ---------------------------------------------------------------------------
__global__ __launch_bounds__(256, 4)
void kc1_conv(const float* __restrict__ inp,
              const float* __restrict__ w1, const float* __restrict__ b1,
              const float* __restrict__ g1, const float* __restrict__ be1,
              const float* __restrict__ m1, const float* __restrict__ v1,
              const float* __restrict__ a1,
              float* __restrict__ Qws)
{
    __shared__ __align__(16) float sW[Cv * DCv];   // 8 KB [k][c]
    __shared__ float sB[DCv];

    const int tid = threadIdx.x;
    const int bid = blockIdx.x;
    const int h   = bid & 1;
    const int bf  = bid >> 1;
    const int b   = bf >> 7;
    const int f   = bf & 127;

    #pragma unroll
    for (int i = 0; i < 8; ++i) {
        const int e = tid * 8 + i;
        const int c = e & 31, k = e >> 5;
        sW[e] = w1[c * Cv + k] * (g1[c] * rsqrtf(v1[c] + 1e-5f));
    }
    if (tid < DCv) {
        const float s = g1[tid] * rsqrtf(v1[tid] + 1e-5f);
        sB[tid] = (b1[tid] - m1[tid]) * s + be1[tid];
    }
    const float alpha1 = a1[0];
    __syncthreads();

    const int w  = tid >> 6, l = tid & 63;
    const int tl = l & 15, cl = l >> 4;
    const int r0 = cl * 8;
    const int t0 = h * 256 + w * 64 + tl * 4;

    const float* px = inp + (size_t)(b * Cv) * FT + f * 512 + t0;

    float acc[32];
    #pragma unroll
    for (int i = 0; i < 32; ++i) acc[i] = 0.f;

    #pragma unroll 8
    for (int k = 0; k < Cv; ++k) {
        const float4 x   = *(const float4*)&px[(size_t)k * FT];
        const float4 a0  = *(const float4*)&sW[k * DCv + r0];
        const float4 a1v = *(const float4*)&sW[k * DCv + r0 + 4];
        acc[0*4+0] = fmaf(a0.x, x.x, acc[0*4+0]); acc[0*4+1] = fmaf(a0.x, x.y, acc[0*4+1]);
        acc[0*4+2] = fmaf(a0.x, x.z, acc[0*4+2]); acc[0*4+3] = fmaf(a0.x, x.w, acc[0*4+3]);
        acc[1*4+0] = fmaf(a0.y, x.x, acc[1*4+0]); acc[1*4+1] = fmaf(a0.y, x.y, acc[1*4+1]);
        acc[1*4+2] = fmaf(a0.y, x.z, acc[1*4+2]); acc[1*4+3] = fmaf(a0.y, x.w, acc[1*4+3]);
        acc[2*4+0] = fmaf(a0.z, x.x, acc[2*4+0]); acc[2*4+1] = fmaf(a0.z, x.y, acc[2*4+1]);
        acc[2*4+2] = fmaf(a0.z, x.z, acc[2*4+2]); acc[2*4+3] = fmaf(a0.z, x.w, acc[2*4+3]);
        acc[3*4+0] = fmaf(a0.w, x.x, acc[3*4+0]); acc[3*4+1] = fmaf(a0.w, x.y, acc[3*4+1]);
        acc[3*4+2] = fmaf(a0.w, x.z, acc[3*4+2]); acc[3*4+3] = fmaf(a0.w, x.w, acc[3*4+3]);
        acc[4*4+0] = fmaf(a1v.x, x.x, acc[4*4+0]); acc[4*4+1] = fmaf(a1v.x, x.y, acc[4*4+1]);
        acc[4*4+2] = fmaf(a1v.x, x.z, acc[4*4+2]); acc[4*4+3] = fmaf(a1v.x, x.w, acc[4*4+3]);
        acc[5*4+0] = fmaf(a1v.y, x.x, acc[5*4+0]); acc[5*4+1] = fmaf(a1v.y, x.y, acc[5*4+1]);
        acc[5*4+2] = fmaf(a1v.y, x.z, acc[5*4+2]); acc[5*4+3] = fmaf(a1v.y, x.w, acc[5*4+3]);
        acc[6*4+0] = fmaf(a1v.z, x.x, acc[6*4+0]); acc[6*4+1] = fmaf(a1v.z, x.y, acc[6*4+1]);
        acc[6*4+2] = fmaf(a1v.z, x.z, acc[6*4+2]); acc[6*4+3] = fmaf(a1v.z, x.w, acc[6*4+3]);
        acc[7*4+0] = fmaf(a1v.w, x.x, acc[7*4+0]); acc[7*4+1] = fmaf(a1v.w, x.y, acc[7*4+1]);
        acc[7*4+2] = fmaf(a1v.w, x.z, acc[7*4+2]); acc[7*4+3] = fmaf(a1v.w, x.w, acc[7*4+3]);
    }

    const float b0 = sB[r0+0], b1_ = sB[r0+1], b2 = sB[r0+2], b3 = sB[r0+3];
    const float b4 = sB[r0+4], b5  = sB[r0+5], b6 = sB[r0+6], b7 = sB[r0+7];
    #pragma unroll
    for (int j = 0; j < 4; ++j) {
        float z0 = acc[0*4+j] + b0, z1 = acc[1*4+j] + b1_;
        float z2 = acc[2*4+j] + b2, z3 = acc[3*4+j] + b3;
        float z4 = acc[4*4+j] + b4, z5 = acc[5*4+j] + b5;
        float z6 = acc[6*4+j] + b6, z7 = acc[7*4+j] + b7;
        z0 = z0 >= 0.f ? z0 : alpha1 * z0;  z1 = z1 >= 0.f ? z1 : alpha1 * z1;
        z2 = z2 >= 0.f ? z2 : alpha1 * z2;  z3 = z3 >= 0.f ? z3 : alpha1 * z3;
        z4 = z4 >= 0.f ? z4 : alpha1 * z4;  z5 = z5 >= 0.f ? z5 : alpha1 * z5;
        z6 = z6 >= 0.f ? z6 : alpha1 * z6;  z7 = z7 >= 0.f ? z7 : alpha1 * z7;
        float4 v0; v0.x = z0; v0.y = z1; v0.z = z2; v0.w = z3;
        float4 v1; v1.x = z4; v1.y = z5; v1.z = z6; v1.w = z7;
        float* qg = Qws + ((size_t)bf * Tv + t0 + j) * DCv + r0;
        *(float4*)&qg[0] = v0;
        *(float4*)&qg[4] = v1;
    }
}

// ---------------------------------------------------------------------------
// KM: M = Q Q^T / sqrt(32). One block per bf (~9 us). [r24 champion]
// ---------------------------------------------------------------------------
__global__ __launch_bounds__(256)
void km_build(const float* __restrict__ Qws, float* __restrict__ Mfull)
{
    __shared__ __align__(16) float sP[4][1024];  // 16 KB

    const int tid   = threadIdx.x;
    const int bf    = blockIdx.x;
    const int slice = tid >> 6;
    const int l     = tid & 63;
    const int c1b   = l >> 3;
    const int c2b   = l & 7;

    const float* qp = Qws + ((size_t)bf * Tv + slice * 128) * DCv;
    float4 r0 = {0,0,0,0}, r1 = {0,0,0,0}, r2 = {0,0,0,0}, r3 = {0,0,0,0};
    #pragma unroll 4
    for (int i = 0; i < 128; ++i) {
        const float4 qa = *(const float4*)&qp[i * 32 + c1b * 4];
        const float4 qb = *(const float4*)&qp[i * 32 + c2b * 4];
        r0.x = fmaf(qa.x, qb.x, r0.x); r0.y = fmaf(qa.x, qb.y, r0.y);
        r0.z = fmaf(qa.x, qb.z, r0.z); r0.w = fmaf(qa.x, qb.w, r0.w);
        r1.x = fmaf(qa.y, qb.x, r1.x); r1.y = fmaf(qa.y, qb.y, r1.y);
        r1.z = fmaf(qa.y, qb.z, r1.z); r1.w = fmaf(qa.y, qb.w, r1.w);
        r2.x = fmaf(qa.z, qb.x, r2.x); r2.y = fmaf(qa.z, qb.y, r2.y);
        r2.z = fmaf(qa.z, qb.z, r2.z); r2.w = fmaf(qa.z, qb.w, r2.w);
        r3.x = fmaf(qa.w, qb.x, r3.x); r3.y = fmaf(qa.w, qb.y, r3.y);
        r3.z = fmaf(qa.w, qb.z, r3.z); r3.w = fmaf(qa.w, qb.w, r3.w);
    }
    *(float4*)&sP[slice][(c1b * 4 + 0) * DCv + c2b * 4] = r0;
    *(float4*)&sP[slice][(c1b * 4 + 1) * DCv + c2b * 4] = r1;
    *(float4*)&sP[slice][(c1b * 4 + 2) * DCv + c2b * 4] = r2;
    *(float4*)&sP[slice][(c1b * 4 + 3) * DCv + c2b * 4] = r3;
    __syncthreads();

    const float INV = 0.17677669529663687f;  // 1/sqrt(32)
    float4 v0 = *(const float4*)&sP[0][tid * 4];
    float4 v1 = *(const float4*)&sP[1][tid * 4];
    float4 v2 = *(const float4*)&sP[2][tid * 4];
    float4 v3 = *(const float4*)&sP[3][tid * 4];
    float4 o;
    o.x = ((v0.x + v1.x) + (v2.x + v3.x)) * INV;
    o.y = ((v0.y + v1.y) + (v2.y + v3.y)) * INV;
    o.z = ((v0.z + v1.z) + (v2.z + v3.z)) * INV;
    o.w = ((v0.w + v1.w) + (v2.w + v3.w)) * INV;
    *(float4*)&Mfull[(size_t)bf * 1024 + tid * 4] = o;
}

// ---------------------------------------------------------------------------
// KF v6 [r24 champion, measured 41 us]: GEMM1 fp32 -> online softmax ->
// P bf16 [t][40] (aliases sX) -> GEMM2 via MFMA swapped (D = P * W2^T ->
// D[t][oc], float4 epilogue). Logit path fp32 (r25 lesson: bf16 logits fail).
// ---------------------------------------------------------------------------
#define GEMM_CC(ACC, cc, a)                                       \
    ACC[(cc)*4+0] = fmaf(a.x, x0.x, ACC[(cc)*4+0]);               \
    ACC[(cc)*4+0] = fmaf(a.y, x1.x, ACC[(cc)*4+0]);               \
    ACC[(cc)*4+0] = fmaf(a.z, x2.x, ACC[(cc)*4+0]);               \
    ACC[(cc)*4+0] = fmaf(a.w, x3.x, ACC[(cc)*4+0]);               \
    ACC[(cc)*4+1] = fmaf(a.x, x0.y, ACC[(cc)*4+1]);               \
    ACC[(cc)*4+1] = fmaf(a.y, x1.y, ACC[(cc)*4+1]);               \
    ACC[(cc)*4+1] = fmaf(a.z, x2.y, ACC[(cc)*4+1]);               \
    ACC[(cc)*4+1] = fmaf(a.w, x3.y, ACC[(cc)*4+1]);               \
    ACC[(cc)*4+2] = fmaf(a.x, x0.z, ACC[(cc)*4+2]);               \
    ACC[(cc)*4+2] = fmaf(a.y, x1.z, ACC[(cc)*4+2]);               \
    ACC[(cc)*4+2] = fmaf(a.z, x2.z, ACC[(cc)*4+2]);               \
    ACC[(cc)*4+2] = fmaf(a.w, x3.z, ACC[(cc)*4+2]);               \
    ACC[(cc)*4+3] = fmaf(a.x, x0.w, ACC[(cc)*4+3]);               \
    ACC[(cc)*4+3] = fmaf(a.y, x1.w, ACC[(cc)*4+3]);               \
    ACC[(cc)*4+3] = fmaf(a.z, x2.w, ACC[(cc)*4+3]);               \
    ACC[(cc)*4+3] = fmaf(a.w, x3.w, ACC[(cc)*4+3]);

__global__ __launch_bounds__(512, 2)
void kf_fused(const float* __restrict__ inp,
              const float* __restrict__ Qws, const float* __restrict__ Mfull,
              const float* __restrict__ wp, const float* __restrict__ bp,
              const float* __restrict__ g2, const float* __restrict__ be2,
              const float* __restrict__ m2, const float* __restrict__ v2,
              const float* __restrict__ a2,
              float* __restrict__ out)
{
    __shared__ __align__(16) float sX[DCv * Tv];          // 64 KB: Q fp32 [k][t], later P bf16 [t][40]
    __shared__ __align__(16) float sM[DCv * 36];          // 4.5 KB
    __shared__ __align__(16) unsigned short sWb[Cv * 40]; // 5 KB: W2 bf16 [oc][k] pad40
    __shared__ float sPartM[8][DCv], sPartS[8][DCv];
    __shared__ float sMx[DCv], sRZ[DCv];
    __shared__ float sB2[Cv];

    const int tid = threadIdx.x;
    const int bf  = blockIdx.x;
    const int b   = bf >> 7;
    const int f   = bf & 127;
    const int w   = tid >> 6;
    const int l   = tid & 63;
    const int tl  = l & 15;
    const int cl  = l >> 4;
    const int t0  = w * 64 + tl * 4;          // this lane's 4 t-columns
    const int limit = f + (Tv - Fv + 1);      // valid iff t < limit (385..512)
    const float alpha2 = a2[0];

    // ---- stage: q column, M (fp32), W2 bf16 (BN-folded), B2 ----
    const float* qg = Qws + ((size_t)bf * Tv + tid) * DCv;
    float4 q0 = *(const float4*)&qg[0],  q1 = *(const float4*)&qg[4];
    float4 q2 = *(const float4*)&qg[8],  q3 = *(const float4*)&qg[12];
    float4 q4 = *(const float4*)&qg[16], q5 = *(const float4*)&qg[20];
    float4 q6 = *(const float4*)&qg[24], q7 = *(const float4*)&qg[28];

    if (tid < 256) {
        const int c = tid >> 3, k0 = (tid & 7) << 2;
        float4 v = *(const float4*)&Mfull[(size_t)bf * 1024 + tid * 4];
        *(float4*)&sM[c * 36 + k0] = v;
    }
    {
        const int oc = tid >> 3, k0 = (tid & 7) << 2;
        const float s = g2[oc] * rsqrtf(v2[oc] + 1e-5f);
        float4 v = *(const float4*)&wp[tid * 4];
        unsigned short* d = &sWb[oc * 40 + k0];
        d[0] = (unsigned short)f2bf(v.x * s);
        d[1] = (unsigned short)f2bf(v.y * s);
        d[2] = (unsigned short)f2bf(v.z * s);
        d[3] = (unsigned short)f2bf(v.w * s);
    }
    if (tid < Cv) {
        const float s = g2[tid] * rsqrtf(v2[tid] + 1e-5f);
        sB2[tid] = (bp[tid] - m2[tid]) * s + be2[tid];
    }

    {
        const int t = tid;
        sX[ 0*Tv+t]=q0.x; sX[ 1*Tv+t]=q0.y; sX[ 2*Tv+t]=q0.z; sX[ 3*Tv+t]=q0.w;
        sX[ 4*Tv+t]=q1.x; sX[ 5*Tv+t]=q1.y; sX[ 6*Tv+t]=q1.z; sX[ 7*Tv+t]=q1.w;
        sX[ 8*Tv+t]=q2.x; sX[ 9*Tv+t]=q2.y; sX[10*Tv+t]=q2.z; sX[11*Tv+t]=q2.w;
        sX[12*Tv+t]=q3.x; sX[13*Tv+t]=q3.y; sX[14*Tv+t]=q3.z; sX[15*Tv+t]=q3.w;
        sX[16*Tv+t]=q4.x; sX[17*Tv+t]=q4.y; sX[18*Tv+t]=q4.z; sX[19*Tv+t]=q4.w;
        sX[20*Tv+t]=q5.x; sX[21*Tv+t]=q5.y; sX[22*Tv+t]=q5.z; sX[23*Tv+t]=q5.w;
        sX[24*Tv+t]=q6.x; sX[25*Tv+t]=q6.y; sX[26*Tv+t]=q6.z; sX[27*Tv+t]=q6.w;
        sX[28*Tv+t]=q7.x; sX[29*Tv+t]=q7.y; sX[30*Tv+t]=q7.z; sX[31*Tv+t]=q7.w;
    }
    __syncthreads();

    // ---- GEMM1 (fp32): O[32c][t], two 4-row tiles sharing x-reads ----
    float oA[16], oB[16];
    #pragma unroll
    for (int i = 0; i < 16; ++i) { oA[i] = 0.f; oB[i] = 0.f; }
    const int cA = cl * 4;
    const int cB = 16 + cl * 4;
    #pragma unroll
    for (int k0 = 0; k0 < 32; k0 += 4) {
        const float4 x0 = *(const float4*)&sX[(k0+0)*Tv + t0];
        const float4 x1 = *(const float4*)&sX[(k0+1)*Tv + t0];
        const float4 x2 = *(const float4*)&sX[(k0+2)*Tv + t0];
        const float4 x3 = *(const float4*)&sX[(k0+3)*Tv + t0];
        { const float4 a = *(const float4*)&sM[(cA+0)*36 + k0]; GEMM_CC(oA,0,a) }
        { const float4 a = *(const float4*)&sM[(cA+1)*36 + k0]; GEMM_CC(oA,1,a) }
        { const float4 a = *(const float4*)&sM[(cA+2)*36 + k0]; GEMM_CC(oA,2,a) }
        { const float4 a = *(const float4*)&sM[(cA+3)*36 + k0]; GEMM_CC(oA,3,a) }
        { const float4 a = *(const float4*)&sM[(cB+0)*36 + k0]; GEMM_CC(oB,0,a) }
        { const float4 a = *(const float4*)&sM[(cB+1)*36 + k0]; GEMM_CC(oB,1,a) }
        { const float4 a = *(const float4*)&sM[(cB+2)*36 + k0]; GEMM_CC(oB,2,a) }
        { const float4 a = *(const float4*)&sM[(cB+3)*36 + k0]; GEMM_CC(oB,3,a) }
    }

    // ---- mask ----
    #pragma unroll
    for (int jt = 0; jt < 4; ++jt) {
        if (t0 + jt >= limit) {
            #pragma unroll
            for (int cc = 0; cc < 4; ++cc) { oA[cc*4+jt] = -INFINITY; oB[cc*4+jt] = -INFINITY; }
        }
    }

    // ---- ONLINE wave stats (one pass): m_w, s_w ----
    float mwA[4], mwB[4];
    #pragma unroll
    for (int cc = 0; cc < 4; ++cc) {
        float mA = fmaxf(fmaxf(oA[cc*4+0], oA[cc*4+1]), fmaxf(oA[cc*4+2], oA[cc*4+3]));
        float mB = fmaxf(fmaxf(oB[cc*4+0], oB[cc*4+1]), fmaxf(oB[cc*4+2], oB[cc*4+3]));
        #pragma unroll
        for (int s = 1; s < 16; s <<= 1) {
            mA = fmaxf(mA, __shfl_xor(mA, s));
            mB = fmaxf(mB, __shfl_xor(mB, s));
        }
        mA = fmaxf(mA, -1e30f);
        mB = fmaxf(mB, -1e30f);
        float sA = 0.f, sB = 0.f;
        #pragma unroll
        for (int jt = 0; jt < 4; ++jt) {
            oA[cc*4+jt] = __expf(oA[cc*4+jt] - mA); sA += oA[cc*4+jt];
            oB[cc*4+jt] = __expf(oB[cc*4+jt] - mB); sB += oB[cc*4+jt];
        }
        #pragma unroll
        for (int s = 1; s < 16; s <<= 1) {
            sA += __shfl_xor(sA, s);
            sB += __shfl_xor(sB, s);
        }
        mwA[cc] = mA; mwB[cc] = mB;
        if (tl == 0) {
            sPartM[w][cA + cc] = mA; sPartS[w][cA + cc] = sA;
            sPartM[w][cB + cc] = mB; sPartS[w][cB + cc] = sB;
        }
    }
    __syncthreads();
    if (tid < DCv) {
        float m = sPartM[0][tid];
        #pragma unroll
        for (int ww = 1; ww < 8; ++ww) m = fmaxf(m, sPartM[ww][tid]);
        float Z = 0.f;
        #pragma unroll
        for (int ww = 0; ww < 8; ++ww) Z += sPartS[ww][tid] * __expf(sPartM[ww][tid] - m);
        sMx[tid] = m;
        sRZ[tid] = 1.f / Z;
    }
    __syncthreads();   // also: all GEMM1 reads of sX complete -> safe to alias

    // ---- P (bf16) -> sPb[t][40] aliasing sX ----
    unsigned short* sPb = (unsigned short*)sX;
    {
        float scAv[4], scBv[4];
        #pragma unroll
        for (int cc = 0; cc < 4; ++cc) {
            scAv[cc] = __expf(mwA[cc] - sMx[cA + cc]) * sRZ[cA + cc];
            scBv[cc] = __expf(mwB[cc] - sMx[cB + cc]) * sRZ[cB + cc];
        }
        #pragma unroll
        for (int jt = 0; jt < 4; ++jt) {
            const int t = t0 + jt;
            uint2 va, vb;
            va.x = f2bf(oA[0*4+jt]*scAv[0]) | (f2bf(oA[1*4+jt]*scAv[1]) << 16);
            va.y = f2bf(oA[2*4+jt]*scAv[2]) | (f2bf(oA[3*4+jt]*scAv[3]) << 16);
            vb.x = f2bf(oB[0*4+jt]*scBv[0]) | (f2bf(oB[1*4+jt]*scBv[1]) << 16);
            vb.y = f2bf(oB[2*4+jt]*scBv[2]) | (f2bf(oB[3*4+jt]*scBv[3]) << 16);
            *(uint2*)&sPb[t * 40 + cA] = va;
            *(uint2*)&sPb[t * 40 + cB] = vb;
        }
    }
    __syncthreads();

    // ---- GEMM2 via MFMA (SWAPPED): D = P * W2^T -> D[t][oc] ----
    {
        const int lr = l & 15, lk = l >> 4;
        bf16x8 afr[4];
        #pragma unroll
        for (int o = 0; o < 4; ++o)
            afr[o] = *(bf16x8*)&sWb[(o * 16 + lr) * 40 + lk * 8];

        #pragma unroll
        for (int tt = 0; tt < 4; ++tt) {
            const int tbase = (w * 4 + tt) * 16;
            const bf16x8 bfr = *(bf16x8*)&sPb[(tbase + lr) * 40 + lk * 8];
            const int trow = tbase + lk * 4;        // this lane's 4 consecutive t
            #pragma unroll
            for (int o = 0; o < 4; ++o) {
                f32x4 d = {0.f, 0.f, 0.f, 0.f};
                d = __builtin_amdgcn_mfma_f32_16x16x32_bf16(bfr, afr[o], d, 0, 0, 0);
                const int oc = o * 16 + lr;
                const float* rp = inp + ((size_t)(b * Cv + oc) * Fv + f) * Tv + trow;
                float*       po = out + ((size_t)(b * Cv + oc) * Fv + f) * Tv + trow;
                const float4 rv = *(const float4*)rp;
                const float bb = sB2[oc];
                float z0 = d[0] + bb, z1 = d[1] + bb, z2 = d[2] + bb, z3 = d[3] + bb;
                z0 = z0 >= 0.f ? z0 : alpha2 * z0;
                z1 = z1 >= 0.f ? z1 : alpha2 * z1;
                z2 = z2 >= 0.f ? z2 : alpha2 * z2;
                z3 = z3 >= 0.f ? z3 : alpha2 * z3;
                float4 o4; o4.x = z0 + rv.x; o4.y = z1 + rv.y;
                o4.z = z2 + rv.z; o4.w = z3 + rv.w;
                *(float4*)po = o4;
            }
        }
    }
}

extern "C" void kernel_launch(void* const* d_in, const int* in_sizes, int n_in,
                              void* d_out, int out_size, void* d_ws, size_t ws_size,
                              hipStream_t stream) {
    const float* inp = (const float*)d_in[0];
    const float* w1  = (const float*)d_in[1];
    const float* b1  = (const float*)d_in[2];
    const float* g1  = (const float*)d_in[3];
    const float* be1 = (const float*)d_in[4];
    const float* m1  = (const float*)d_in[5];
    const float* v1  = (const float*)d_in[6];
    const float* a1  = (const float*)d_in[7];
    const float* wp  = (const float*)d_in[8];
    const float* bp  = (const float*)d_in[9];
    const float* g2  = (const float*)d_in[10];
    const float* be2 = (const float*)d_in[11];
    const float* m2  = (const float*)d_in[12];
    const float* v2  = (const float*)d_in[13];
    const float* a2  = (const float*)d_in[14];

    float* Qws   = (float*)d_ws;                            // 8,388,608 f = 33.6 MB
    float* Mfull = Qws + (size_t)Bv * Fv * Tv * DCv;        //   524,288 f =  2.1 MB

    kc1_conv<<<dim3(Bv * Fv * 2), dim3(256), 0, stream>>>(
        inp, w1, b1, g1, be1, m1, v1, a1, Qws);
    km_build<<<dim3(Bv * Fv), dim3(256), 0, stream>>>(Qws, Mfull);
    kf_fused<<<dim3(Bv * Fv), dim3(512), 0, stream>>>(
        inp, Qws, Mfull, wp, bp, g2, be2, m2, v2, a2, (float*)d_out);
}

// Round 27
// 75.920 us; speedup vs baseline: 1.1773x; 1.0781x over previous
//
#include <hip/hip_runtime.h>
#include <math.h>

#define Bv  4
#define Cv  64
#define DCv 32
#define Fv  128
#define Tv  512
#define FT  (Fv * 512)

typedef __attribute__((ext_vector_type(8))) short bf16x8;
typedef __attribute__((ext_vector_type(4))) float f32x4;

__device__ __forceinline__ unsigned f2bf(float x) {          // RNE pack
    unsigned u = __float_as_uint(x);
    return (u + 0x7FFFu + ((u >> 16) & 1u)) >> 16;
}

// ---------------------------------------------------------------------------
// KC1: conv1, 8-row x 4-t register tile (~27 us). [champion, byte-identical]
// ---------------------------------------------------------------------------
__global__ __launch_bounds__(256, 4)
void kc1_conv(const float* __restrict__ inp,
              const float* __restrict__ w1, const float* __restrict__ b1,
              const float* __restrict__ g1, const float* __restrict__ be1,
              const float* __restrict__ m1, const float* __restrict__ v1,
              const float* __restrict__ a1,
              float* __restrict__ Qws)
{
    __shared__ __align__(16) float sW[Cv * DCv];   // 8 KB [k][c]
    __shared__ float sB[DCv];

    const int tid = threadIdx.x;
    const int bid = blockIdx.x;
    const int h   = bid & 1;
    const int bf  = bid >> 1;
    const int b   = bf >> 7;
    const int f   = bf & 127;

    #pragma unroll
    for (int i = 0; i < 8; ++i) {
        const int e = tid * 8 + i;
        const int c = e & 31, k = e >> 5;
        sW[e] = w1[c * Cv + k] * (g1[c] * rsqrtf(v1[c] + 1e-5f));
    }
    if (tid < DCv) {
        const float s = g1[tid] * rsqrtf(v1[tid] + 1e-5f);
        sB[tid] = (b1[tid] - m1[tid]) * s + be1[tid];
    }
    const float alpha1 = a1[0];
    __syncthreads();

    const int w  = tid >> 6, l = tid & 63;
    const int tl = l & 15, cl = l >> 4;
    const int r0 = cl * 8;
    const int t0 = h * 256 + w * 64 + tl * 4;

    const float* px = inp + (size_t)(b * Cv) * FT + f * 512 + t0;

    float acc[32];
    #pragma unroll
    for (int i = 0; i < 32; ++i) acc[i] = 0.f;

    #pragma unroll 8
    for (int k = 0; k < Cv; ++k) {
        const float4 x   = *(const float4*)&px[(size_t)k * FT];
        const float4 a0  = *(const float4*)&sW[k * DCv + r0];
        const float4 a1v = *(const float4*)&sW[k * DCv + r0 + 4];
        acc[0*4+0] = fmaf(a0.x, x.x, acc[0*4+0]); acc[0*4+1] = fmaf(a0.x, x.y, acc[0*4+1]);
        acc[0*4+2] = fmaf(a0.x, x.z, acc[0*4+2]); acc[0*4+3] = fmaf(a0.x, x.w, acc[0*4+3]);
        acc[1*4+0] = fmaf(a0.y, x.x, acc[1*4+0]); acc[1*4+1] = fmaf(a0.y, x.y, acc[1*4+1]);
        acc[1*4+2] = fmaf(a0.y, x.z, acc[1*4+2]); acc[1*4+3] = fmaf(a0.y, x.w, acc[1*4+3]);
        acc[2*4+0] = fmaf(a0.z, x.x, acc[2*4+0]); acc[2*4+1] = fmaf(a0.z, x.y, acc[2*4+1]);
        acc[2*4+2] = fmaf(a0.z, x.z, acc[2*4+2]); acc[2*4+3] = fmaf(a0.z, x.w, acc[2*4+3]);
        acc[3*4+0] = fmaf(a0.w, x.x, acc[3*4+0]); acc[3*4+1] = fmaf(a0.w, x.y, acc[3*4+1]);
        acc[3*4+2] = fmaf(a0.w, x.z, acc[3*4+2]); acc[3*4+3] = fmaf(a0.w, x.w, acc[3*4+3]);
        acc[4*4+0] = fmaf(a1v.x, x.x, acc[4*4+0]); acc[4*4+1] = fmaf(a1v.x, x.y, acc[4*4+1]);
        acc[4*4+2] = fmaf(a1v.x, x.z, acc[4*4+2]); acc[4*4+3] = fmaf(a1v.x, x.w, acc[4*4+3]);
        acc[5*4+0] = fmaf(a1v.y, x.x, acc[5*4+0]); acc[5*4+1] = fmaf(a1v.y, x.y, acc[5*4+1]);
        acc[5*4+2] = fmaf(a1v.y, x.z, acc[5*4+2]); acc[5*4+3] = fmaf(a1v.y, x.w, acc[5*4+3]);
        acc[6*4+0] = fmaf(a1v.z, x.x, acc[6*4+0]); acc[6*4+1] = fmaf(a1v.z, x.y, acc[6*4+1]);
        acc[6*4+2] = fmaf(a1v.z, x.z, acc[6*4+2]); acc[6*4+3] = fmaf(a1v.z, x.w, acc[6*4+3]);
        acc[7*4+0] = fmaf(a1v.w, x.x, acc[7*4+0]); acc[7*4+1] = fmaf(a1v.w, x.y, acc[7*4+1]);
        acc[7*4+2] = fmaf(a1v.w, x.z, acc[7*4+2]); acc[7*4+3] = fmaf(a1v.w, x.w, acc[7*4+3]);
    }

    const float b0 = sB[r0+0], b1_ = sB[r0+1], b2 = sB[r0+2], b3 = sB[r0+3];
    const float b4 = sB[r0+4], b5  = sB[r0+5], b6 = sB[r0+6], b7 = sB[r0+7];
    #pragma unroll
    for (int j = 0; j < 4; ++j) {
        float z0 = acc[0*4+j] + b0, z1 = acc[1*4+j] + b1_;
        float z2 = acc[2*4+j] + b2, z3 = acc[3*4+j] + b3;
        float z4 = acc[4*4+j] + b4, z5 = acc[5*4+j] + b5;
        float z6 = acc[6*4+j] + b6, z7 = acc[7*4+j] + b7;
        z0 = z0 >= 0.f ? z0 : alpha1 * z0;  z1 = z1 >= 0.f ? z1 : alpha1 * z1;
        z2 = z2 >= 0.f ? z2 : alpha1 * z2;  z3 = z3 >= 0.f ? z3 : alpha1 * z3;
        z4 = z4 >= 0.f ? z4 : alpha1 * z4;  z5 = z5 >= 0.f ? z5 : alpha1 * z5;
        z6 = z6 >= 0.f ? z6 : alpha1 * z6;  z7 = z7 >= 0.f ? z7 : alpha1 * z7;
        float4 v0; v0.x = z0; v0.y = z1; v0.z = z2; v0.w = z3;
        float4 v1; v1.x = z4; v1.y = z5; v1.z = z6; v1.w = z7;
        float* qg = Qws + ((size_t)bf * Tv + t0 + j) * DCv + r0;
        *(float4*)&qg[0] = v0;
        *(float4*)&qg[4] = v1;
    }
}

// ---------------------------------------------------------------------------
// KM: M = Q Q^T / sqrt(32). One block per bf (~9 us). [champion]
// ---------------------------------------------------------------------------
__global__ __launch_bounds__(256)
void km_build(const float* __restrict__ Qws, float* __restrict__ Mfull)
{
    __shared__ __align__(16) float sP[4][1024];  // 16 KB

    const int tid   = threadIdx.x;
    const int bf    = blockIdx.x;
    const int slice = tid >> 6;
    const int l     = tid & 63;
    const int c1b   = l >> 3;
    const int c2b   = l & 7;

    const float* qp = Qws + ((size_t)bf * Tv + slice * 128) * DCv;
    float4 r0 = {0,0,0,0}, r1 = {0,0,0,0}, r2 = {0,0,0,0}, r3 = {0,0,0,0};
    #pragma unroll 4
    for (int i = 0; i < 128; ++i) {
        const float4 qa = *(const float4*)&qp[i * 32 + c1b * 4];
        const float4 qb = *(const float4*)&qp[i * 32 + c2b * 4];
        r0.x = fmaf(qa.x, qb.x, r0.x); r0.y = fmaf(qa.x, qb.y, r0.y);
        r0.z = fmaf(qa.x, qb.z, r0.z); r0.w = fmaf(qa.x, qb.w, r0.w);
        r1.x = fmaf(qa.y, qb.x, r1.x); r1.y = fmaf(qa.y, qb.y, r1.y);
        r1.z = fmaf(qa.y, qb.z, r1.z); r1.w = fmaf(qa.y, qb.w, r1.w);
        r2.x = fmaf(qa.z, qb.x, r2.x); r2.y = fmaf(qa.z, qb.y, r2.y);
        r2.z = fmaf(qa.z, qb.z, r2.z); r2.w = fmaf(qa.z, qb.w, r2.w);
        r3.x = fmaf(qa.w, qb.x, r3.x); r3.y = fmaf(qa.w, qb.y, r3.y);
        r3.z = fmaf(qa.w, qb.z, r3.z); r3.w = fmaf(qa.w, qb.w, r3.w);
    }
    *(float4*)&sP[slice][(c1b * 4 + 0) * DCv + c2b * 4] = r0;
    *(float4*)&sP[slice][(c1b * 4 + 1) * DCv + c2b * 4] = r1;
    *(float4*)&sP[slice][(c1b * 4 + 2) * DCv + c2b * 4] = r2;
    *(float4*)&sP[slice][(c1b * 4 + 3) * DCv + c2b * 4] = r3;
    __syncthreads();

    const float INV = 0.17677669529663687f;  // 1/sqrt(32)
    float4 v0 = *(const float4*)&sP[0][tid * 4];
    float4 v1 = *(const float4*)&sP[1][tid * 4];
    float4 v2 = *(const float4*)&sP[2][tid * 4];
    float4 v3 = *(const float4*)&sP[3][tid * 4];
    float4 o;
    o.x = ((v0.x + v1.x) + (v2.x + v3.x)) * INV;
    o.y = ((v0.y + v1.y) + (v2.y + v3.y)) * INV;
    o.z = ((v0.z + v1.z) + (v2.z + v3.z)) * INV;
    o.w = ((v0.w + v1.w) + (v2.w + v3.w)) * INV;
    *(float4*)&Mfull[(size_t)bf * 1024 + tid * 4] = o;
}

// ---------------------------------------------------------------------------
// KF v6b: identical to champion except GEMM2 loop order swapped (o outer,
// tt inner) with preloaded P-fragments -> each oc-row's 256 B of writes
// issue back-to-back (full-line write combining; was 64 B chunks).
// ---------------------------------------------------------------------------
#define GEMM_CC(ACC, cc, a)                                       \
    ACC[(cc)*4+0] = fmaf(a.x, x0.x, ACC[(cc)*4+0]);               \
    ACC[(cc)*4+0] = fmaf(a.y, x1.x, ACC[(cc)*4+0]);               \
    ACC[(cc)*4+0] = fmaf(a.z, x2.x, ACC[(cc)*4+0]);               \
    ACC[(cc)*4+0] = fmaf(a.w, x3.x, ACC[(cc)*4+0]);               \
    ACC[(cc)*4+1] = fmaf(a.x, x0.y, ACC[(cc)*4+1]);               \
    ACC[(cc)*4+1] = fmaf(a.y, x1.y, ACC[(cc)*4+1]);               \
    ACC[(cc)*4+1] = fmaf(a.z, x2.y, ACC[(cc)*4+1]);               \
    ACC[(cc)*4+1] = fmaf(a.w, x3.y, ACC[(cc)*4+1]);               \
    ACC[(cc)*4+2] = fmaf(a.x, x0.z, ACC[(cc)*4+2]);               \
    ACC[(cc)*4+2] = fmaf(a.y, x1.z, ACC[(cc)*4+2]);               \
    ACC[(cc)*4+2] = fmaf(a.z, x2.z, ACC[(cc)*4+2]);               \
    ACC[(cc)*4+2] = fmaf(a.w, x3.z, ACC[(cc)*4+2]);               \
    ACC[(cc)*4+3] = fmaf(a.x, x0.w, ACC[(cc)*4+3]);               \
    ACC[(cc)*4+3] = fmaf(a.y, x1.w, ACC[(cc)*4+3]);               \
    ACC[(cc)*4+3] = fmaf(a.z, x2.w, ACC[(cc)*4+3]);               \
    ACC[(cc)*4+3] = fmaf(a.w, x3.w, ACC[(cc)*4+3]);

__global__ __launch_bounds__(512, 2)
void kf_fused(const float* __restrict__ inp,
              const float* __restrict__ Qws, const float* __restrict__ Mfull,
              const float* __restrict__ wp, const float* __restrict__ bp,
              const float* __restrict__ g2, const float* __restrict__ be2,
              const float* __restrict__ m2, const float* __restrict__ v2,
              const float* __restrict__ a2,
              float* __restrict__ out)
{
    __shared__ __align__(16) float sX[DCv * Tv];          // 64 KB: Q fp32 [k][t], later P bf16 [t][40]
    __shared__ __align__(16) float sM[DCv * 36];          // 4.5 KB
    __shared__ __align__(16) unsigned short sWb[Cv * 40]; // 5 KB: W2 bf16 [oc][k] pad40
    __shared__ float sPartM[8][DCv], sPartS[8][DCv];
    __shared__ float sMx[DCv], sRZ[DCv];
    __shared__ float sB2[Cv];

    const int tid = threadIdx.x;
    const int bf  = blockIdx.x;
    const int b   = bf >> 7;
    const int f   = bf & 127;
    const int w   = tid >> 6;
    const int l   = tid & 63;
    const int tl  = l & 15;
    const int cl  = l >> 4;
    const int t0  = w * 64 + tl * 4;          // this lane's 4 t-columns
    const int limit = f + (Tv - Fv + 1);      // valid iff t < limit (385..512)
    const float alpha2 = a2[0];

    // ---- stage: q column, M (fp32), W2 bf16 (BN-folded), B2 ----
    const float* qg = Qws + ((size_t)bf * Tv + tid) * DCv;
    float4 q0 = *(const float4*)&qg[0],  q1 = *(const float4*)&qg[4];
    float4 q2 = *(const float4*)&qg[8],  q3 = *(const float4*)&qg[12];
    float4 q4 = *(const float4*)&qg[16], q5 = *(const float4*)&qg[20];
    float4 q6 = *(const float4*)&qg[24], q7 = *(const float4*)&qg[28];

    if (tid < 256) {
        const int c = tid >> 3, k0 = (tid & 7) << 2;
        float4 v = *(const float4*)&Mfull[(size_t)bf * 1024 + tid * 4];
        *(float4*)&sM[c * 36 + k0] = v;
    }
    {
        const int oc = tid >> 3, k0 = (tid & 7) << 2;
        const float s = g2[oc] * rsqrtf(v2[oc] + 1e-5f);
        float4 v = *(const float4*)&wp[tid * 4];
        unsigned short* d = &sWb[oc * 40 + k0];
        d[0] = (unsigned short)f2bf(v.x * s);
        d[1] = (unsigned short)f2bf(v.y * s);
        d[2] = (unsigned short)f2bf(v.z * s);
        d[3] = (unsigned short)f2bf(v.w * s);
    }
    if (tid < Cv) {
        const float s = g2[tid] * rsqrtf(v2[tid] + 1e-5f);
        sB2[tid] = (bp[tid] - m2[tid]) * s + be2[tid];
    }

    {
        const int t = tid;
        sX[ 0*Tv+t]=q0.x; sX[ 1*Tv+t]=q0.y; sX[ 2*Tv+t]=q0.z; sX[ 3*Tv+t]=q0.w;
        sX[ 4*Tv+t]=q1.x; sX[ 5*Tv+t]=q1.y; sX[ 6*Tv+t]=q1.z; sX[ 7*Tv+t]=q1.w;
        sX[ 8*Tv+t]=q2.x; sX[ 9*Tv+t]=q2.y; sX[10*Tv+t]=q2.z; sX[11*Tv+t]=q2.w;
        sX[12*Tv+t]=q3.x; sX[13*Tv+t]=q3.y; sX[14*Tv+t]=q3.z; sX[15*Tv+t]=q3.w;
        sX[16*Tv+t]=q4.x; sX[17*Tv+t]=q4.y; sX[18*Tv+t]=q4.z; sX[19*Tv+t]=q4.w;
        sX[20*Tv+t]=q5.x; sX[21*Tv+t]=q5.y; sX[22*Tv+t]=q5.z; sX[23*Tv+t]=q5.w;
        sX[24*Tv+t]=q6.x; sX[25*Tv+t]=q6.y; sX[26*Tv+t]=q6.z; sX[27*Tv+t]=q6.w;
        sX[28*Tv+t]=q7.x; sX[29*Tv+t]=q7.y; sX[30*Tv+t]=q7.z; sX[31*Tv+t]=q7.w;
    }
    __syncthreads();

    // ---- GEMM1 (fp32): O[32c][t], two 4-row tiles sharing x-reads ----
    float oA[16], oB[16];
    #pragma unroll
    for (int i = 0; i < 16; ++i) { oA[i] = 0.f; oB[i] = 0.f; }
    const int cA = cl * 4;
    const int cB = 16 + cl * 4;
    #pragma unroll
    for (int k0 = 0; k0 < 32; k0 += 4) {
        const float4 x0 = *(const float4*)&sX[(k0+0)*Tv + t0];
        const float4 x1 = *(const float4*)&sX[(k0+1)*Tv + t0];
        const float4 x2 = *(const float4*)&sX[(k0+2)*Tv + t0];
        const float4 x3 = *(const float4*)&sX[(k0+3)*Tv + t0];
        { const float4 a = *(const float4*)&sM[(cA+0)*36 + k0]; GEMM_CC(oA,0,a) }
        { const float4 a = *(const float4*)&sM[(cA+1)*36 + k0]; GEMM_CC(oA,1,a) }
        { const float4 a = *(const float4*)&sM[(cA+2)*36 + k0]; GEMM_CC(oA,2,a) }
        { const float4 a = *(const float4*)&sM[(cA+3)*36 + k0]; GEMM_CC(oA,3,a) }
        { const float4 a = *(const float4*)&sM[(cB+0)*36 + k0]; GEMM_CC(oB,0,a) }
        { const float4 a = *(const float4*)&sM[(cB+1)*36 + k0]; GEMM_CC(oB,1,a) }
        { const float4 a = *(const float4*)&sM[(cB+2)*36 + k0]; GEMM_CC(oB,2,a) }
        { const float4 a = *(const float4*)&sM[(cB+3)*36 + k0]; GEMM_CC(oB,3,a) }
    }

    // ---- mask ----
    #pragma unroll
    for (int jt = 0; jt < 4; ++jt) {
        if (t0 + jt >= limit) {
            #pragma unroll
            for (int cc = 0; cc < 4; ++cc) { oA[cc*4+jt] = -INFINITY; oB[cc*4+jt] = -INFINITY; }
        }
    }

    // ---- ONLINE wave stats (one pass): m_w, s_w ----
    float mwA[4], mwB[4];
    #pragma unroll
    for (int cc = 0; cc < 4; ++cc) {
        float mA = fmaxf(fmaxf(oA[cc*4+0], oA[cc*4+1]), fmaxf(oA[cc*4+2], oA[cc*4+3]));
        float mB = fmaxf(fmaxf(oB[cc*4+0], oB[cc*4+1]), fmaxf(oB[cc*4+2], oB[cc*4+3]));
        #pragma unroll
        for (int s = 1; s < 16; s <<= 1) {
            mA = fmaxf(mA, __shfl_xor(mA, s));
            mB = fmaxf(mB, __shfl_xor(mB, s));
        }
        mA = fmaxf(mA, -1e30f);
        mB = fmaxf(mB, -1e30f);
        float sA = 0.f, sB = 0.f;
        #pragma unroll
        for (int jt = 0; jt < 4; ++jt) {
            oA[cc*4+jt] = __expf(oA[cc*4+jt] - mA); sA += oA[cc*4+jt];
            oB[cc*4+jt] = __expf(oB[cc*4+jt] - mB); sB += oB[cc*4+jt];
        }
        #pragma unroll
        for (int s = 1; s < 16; s <<= 1) {
            sA += __shfl_xor(sA, s);
            sB += __shfl_xor(sB, s);
        }
        mwA[cc] = mA; mwB[cc] = mB;
        if (tl == 0) {
            sPartM[w][cA + cc] = mA; sPartS[w][cA + cc] = sA;
            sPartM[w][cB + cc] = mB; sPartS[w][cB + cc] = sB;
        }
    }
    __syncthreads();
    if (tid < DCv) {
        float m = sPartM[0][tid];
        #pragma unroll
        for (int ww = 1; ww < 8; ++ww) m = fmaxf(m, sPartM[ww][tid]);
        float Z = 0.f;
        #pragma unroll
        for (int ww = 0; ww < 8; ++ww) Z += sPartS[ww][tid] * __expf(sPartM[ww][tid] - m);
        sMx[tid] = m;
        sRZ[tid] = 1.f / Z;
    }
    __syncthreads();   // also: all GEMM1 reads of sX complete -> safe to alias

    // ---- P (bf16) -> sPb[t][40] aliasing sX ----
    unsigned short* sPb = (unsigned short*)sX;
    {
        float scAv[4], scBv[4];
        #pragma unroll
        for (int cc = 0; cc < 4; ++cc) {
            scAv[cc] = __expf(mwA[cc] - sMx[cA + cc]) * sRZ[cA + cc];
            scBv[cc] = __expf(mwB[cc] - sMx[cB + cc]) * sRZ[cB + cc];
        }
        #pragma unroll
        for (int jt = 0; jt < 4; ++jt) {
            const int t = t0 + jt;
            uint2 va, vb;
            va.x = f2bf(oA[0*4+jt]*scAv[0]) | (f2bf(oA[1*4+jt]*scAv[1]) << 16);
            va.y = f2bf(oA[2*4+jt]*scAv[2]) | (f2bf(oA[3*4+jt]*scAv[3]) << 16);
            vb.x = f2bf(oB[0*4+jt]*scBv[0]) | (f2bf(oB[1*4+jt]*scBv[1]) << 16);
            vb.y = f2bf(oB[2*4+jt]*scBv[2]) | (f2bf(oB[3*4+jt]*scBv[3]) << 16);
            *(uint2*)&sPb[t * 40 + cA] = va;
            *(uint2*)&sPb[t * 40 + cB] = vb;
        }
    }
    __syncthreads();

    // ---- GEMM2 via MFMA (swapped operands): D = P * W2^T -> D[t][oc] ----
    // Loop order o OUTER / tt INNER: per oc-row, the wave's 4 float4 stores
    // (256 B contiguous t) issue back-to-back -> full-line write combining.
    {
        const int lr = l & 15, lk = l >> 4;
        bf16x8 afr[4], pfr[4];
        #pragma unroll
        for (int o = 0; o < 4; ++o)
            afr[o] = *(bf16x8*)&sWb[(o * 16 + lr) * 40 + lk * 8];
        #pragma unroll
        for (int tt = 0; tt < 4; ++tt)
            pfr[tt] = *(bf16x8*)&sPb[((w * 4 + tt) * 16 + lr) * 40 + lk * 8];

        #pragma unroll
        for (int o = 0; o < 4; ++o) {
            const int oc = o * 16 + lr;
            const float bb = sB2[oc];
            const float* rrow = inp + ((size_t)(b * Cv + oc) * Fv + f) * Tv;
            float*       orow = out + ((size_t)(b * Cv + oc) * Fv + f) * Tv;
            #pragma unroll
            for (int tt = 0; tt < 4; ++tt) {
                f32x4 d = {0.f, 0.f, 0.f, 0.f};
                d = __builtin_amdgcn_mfma_f32_16x16x32_bf16(pfr[tt], afr[o], d, 0, 0, 0);
                const int trow = (w * 4 + tt) * 16 + lk * 4;
                const float4 rv = *(const float4*)&rrow[trow];
                float z0 = d[0] + bb, z1 = d[1] + bb, z2 = d[2] + bb, z3 = d[3] + bb;
                z0 = z0 >= 0.f ? z0 : alpha2 * z0;
                z1 = z1 >= 0.f ? z1 : alpha2 * z1;
                z2 = z2 >= 0.f ? z2 : alpha2 * z2;
                z3 = z3 >= 0.f ? z3 : alpha2 * z3;
                float4 o4; o4.x = z0 + rv.x; o4.y = z1 + rv.y;
                o4.z = z2 + rv.z; o4.w = z3 + rv.w;
                *(float4*)&orow[trow] = o4;
            }
        }
    }
}

extern "C" void kernel_launch(void* const* d_in, const int* in_sizes, int n_in,
                              void* d_out, int out_size, void* d_ws, size_t ws_size,
                              hipStream_t stream) {
    const float* inp = (const float*)d_in[0];
    const float* w1  = (const float*)d_in[1];
    const float* b1  = (const float*)d_in[2];
    const float* g1  = (const float*)d_in[3];
    const float* be1 = (const float*)d_in[4];
    const float* m1  = (const float*)d_in[5];
    const float* v1  = (const float*)d_in[6];
    const float* a1  = (const float*)d_in[7];
    const float* wp  = (const float*)d_in[8];
    const float* bp  = (const float*)d_in[9];
    const float* g2  = (const float*)d_in[10];
    const float* be2 = (const float*)d_in[11];
    const float* m2  = (const float*)d_in[12];
    const float* v2  = (const float*)d_in[13];
    const float* a2  = (const float*)d_in[14];

    float* Qws   = (float*)d_ws;                            // 8,388,608 f = 33.6 MB
    float* Mfull = Qws + (size_t)Bv * Fv * Tv * DCv;        //   524,288 f =  2.1 MB

    kc1_conv<<<dim3(Bv * Fv * 2), dim3(256), 0, stream>>>(
        inp, w1, b1, g1, be1, m1, v1, a1, Qws);
    km_build<<<dim3(Bv * Fv), dim3(256), 0, stream>>>(Qws, Mfull);
    kf_fused<<<dim3(Bv * Fv), dim3(512), 0, stream>>>(
        inp, Qws, Mfull, wp, bp, g2, be2, m2, v2, a2, (float*)d_out);
}